// Round 5
// baseline (5123.701 us; speedup 1.0000x reference)
//
#include <hip/hip_runtime.h>
#include <cstdio>

#define NTOT 175616   // 56^3
#define CDIM 96
#define NPOS 343      // 7^3
#define NWIN 512      // 8^3
#define HIDD 384
#define SLOT 16859136 // NWIN*CDIM*NPOS = NTOT*CDIM
#define SCALE 0.10206207261596577f  // 1/sqrt(96)

// ---------------------------------------------------------------- K1: LN1 + roll(-3) + window partition -> Xw[win][c][p]
__global__ __launch_bounds__(256) void k_ln1(const float* __restrict__ x,
                                             const float* __restrict__ g,
                                             const float* __restrict__ b,
                                             float* __restrict__ Xw) {
  int win = blockIdx.x;
  int p0 = blockIdx.y * 64;
  int cnt = min(64, NPOS - p0);
  int wz = win >> 6, wy = (win >> 3) & 7, wx = win & 7;
  __shared__ float raw[CDIM][64];
  __shared__ float psum[4][64], psq[4][64];
  __shared__ float mean[64], rstd[64];
  int tid = threadIdx.x;
  for (int idx = tid; idx < CDIM * 64; idx += 256) {
    int c = idx >> 6, pp = idx & 63;
    float v = 0.f;
    if (pp < cnt) {
      int p = p0 + pp;
      int lz = p / 49, ly = (p / 7) % 7, lx = p % 7;
      int s = (wz * 7 + lz + 3) % 56;
      int h = (wy * 7 + ly + 3) % 56;
      int w = (wx * 7 + lx + 3) % 56;
      v = x[c * NTOT + (s * 3136 + h * 56 + w)];
    }
    raw[c][pp] = v;
  }
  __syncthreads();
  {
    int pp = tid & 63, grp = tid >> 6;
    float s = 0.f, s2 = 0.f;
    for (int i = 0; i < 24; i++) { float v = raw[grp * 24 + i][pp]; s += v; s2 += v * v; }
    psum[grp][pp] = s; psq[grp][pp] = s2;
  }
  __syncthreads();
  if (tid < 64) {
    float s = psum[0][tid] + psum[1][tid] + psum[2][tid] + psum[3][tid];
    float s2 = psq[0][tid] + psq[1][tid] + psq[2][tid] + psq[3][tid];
    float m = s * (1.f / 96.f);
    float var = s2 * (1.f / 96.f) - m * m;
    mean[tid] = m;
    rstd[tid] = 1.f / sqrtf(var + 1e-5f);
  }
  __syncthreads();
  for (int idx = tid; idx < CDIM * 64; idx += 256) {
    int c = idx >> 6, pp = idx & 63;
    if (pp < cnt) {
      float v = (raw[c][pp] - mean[pp]) * rstd[pp] * g[c] + b[c];
      Xw[(win * CDIM + c) * NPOS + p0 + pp] = v;
    }
  }
}

// ---------------------------------------------------------------- K2: conv1x1 (GEMM) + depthwise 3x3x3 per window
// blockIdx: (win, tensor q/k/v, o-chunk of 32). q,v -> [win][p][c]; k -> [win][c][p]
__global__ __launch_bounds__(256) void k_qkv(
    const float* __restrict__ Xw,
    const float* __restrict__ wq, const float* __restrict__ bq, const float* __restrict__ dqw, const float* __restrict__ dqb,
    const float* __restrict__ wk, const float* __restrict__ bk, const float* __restrict__ dkw, const float* __restrict__ dkb,
    const float* __restrict__ wv, const float* __restrict__ bv, const float* __restrict__ dvw, const float* __restrict__ dvb,
    float* __restrict__ qo, float* __restrict__ kTo, float* __restrict__ vo) {
  int win = blockIdx.x, t = blockIdx.y, ob = blockIdx.z * 32;
  const float *W, *B, *DW, *DB; float* O; bool pfast;
  if (t == 0)      { W = wq; B = bq; DW = dqw; DB = dqb; O = qo;  pfast = false; }
  else if (t == 1) { W = wk; B = bk; DW = dkw; DB = dkb; O = kTo; pfast = true;  }
  else             { W = wv; B = bv; DW = dvw; DB = dvb; O = vo;  pfast = false; }
  __shared__ float wA[32][96];
  __shared__ float dwl[32][27];
  __shared__ float tl[32][345];
  int tid = threadIdx.x, lane = tid & 63, wvi = tid >> 6;
  for (int idx = tid; idx < 32 * 96; idx += 256) wA[idx / 96][idx % 96] = W[(ob + idx / 96) * 96 + idx % 96];
  for (int idx = tid; idx < 32 * 27; idx += 256) dwl[idx / 27][idx % 27] = DW[(ob + idx / 27) * 27 + idx % 27];
  __syncthreads();
  const float* xp = Xw + (size_t)win * CDIM * NPOS;
  for (int pb = 0; pb < 6; pb++) {
    int p = pb * 64 + lane;
    if (p < NPOS) {
      float acc[8];
#pragma unroll
      for (int i = 0; i < 8; i++) acc[i] = B[ob + wvi * 8 + i];
      for (int c = 0; c < 96; c++) {
        float xv = xp[c * NPOS + p];
#pragma unroll
        for (int i = 0; i < 8; i++) acc[i] += wA[wvi * 8 + i][c] * xv;
      }
#pragma unroll
      for (int i = 0; i < 8; i++) tl[wvi * 8 + i][p] = acc[i];
    }
  }
  __syncthreads();
  for (int idx = tid; idx < 32 * NPOS; idx += 256) {
    int o, p;
    if (pfast) { o = idx / NPOS; p = idx - o * NPOS; }
    else       { o = idx & 31;  p = idx >> 5; }
    int lz = p / 49, r1 = p - lz * 49, ly = r1 / 7, lx = r1 - ly * 7;
    float acc = DB[ob + o];
    for (int dz = -1; dz <= 1; dz++) {
      int z = lz + dz; if ((unsigned)z >= 7u) continue;
      for (int dy = -1; dy <= 1; dy++) {
        int y = ly + dy; if ((unsigned)y >= 7u) continue;
        for (int dx = -1; dx <= 1; dx++) {
          int xx = lx + dx; if ((unsigned)xx >= 7u) continue;
          acc += dwl[o][(dz + 1) * 9 + (dy + 1) * 3 + (dx + 1)] * tl[o][z * 49 + y * 7 + xx];
        }
      }
    }
    if (pfast) O[((size_t)win * CDIM + ob + o) * NPOS + p] = acc;
    else       O[((size_t)win * NPOS + p) * CDIM + ob + o] = acc;
  }
}

// ---------------------------------------------------------------- K3: windowed attention, fp32, mask from region ids
// writes attoutT[win][c][r]  (equals the torch axis-mixing trick when read flat)
#define RG 48
__global__ __launch_bounds__(256) void k_attn(const float* __restrict__ q,
                                              const float* __restrict__ kT,
                                              const float* __restrict__ v,
                                              float* __restrict__ attoutT) {
  int win = blockIdx.x;
  int wz = win >> 6, wy = (win >> 3) & 7, wx = win & 7;
  __shared__ __attribute__((aligned(16))) float S[RG * 384];
  __shared__ __attribute__((aligned(16))) float qs[RG * 96];
  __shared__ __attribute__((aligned(16))) float kvf[96 * 64];
  __shared__ int rid[NPOS];
  int tid = threadIdx.x, lane = tid & 63, wvi = tid >> 6;
  for (int p = tid; p < NPOS; p += 256) {
    int lz = p / 49, r1 = p - lz * 49, ly = r1 / 7, lx = r1 - ly * 7;
    int az = wz * 7 + lz, ay = wy * 7 + ly, ax = wx * 7 + lx;
    int rz = (az < 49) ? 0 : ((az < 53) ? 1 : 2);
    int ry = (ay < 49) ? 0 : ((ay < 53) ? 1 : 2);
    int rx = (ax < 49) ? 0 : ((ax < 53) ? 1 : 2);
    rid[p] = rz * 9 + ry * 3 + rx;
  }
  for (int idx = tid; idx < RG * 41; idx += 256) {  // zero pad cols 343..383
    int rr = idx / 41, m = 343 + idx - (idx / 41) * 41;
    S[rr * 384 + m] = 0.f;
  }
  for (int r0 = 0; r0 < NPOS; r0 += RG) {
    int nr = min(RG, NPOS - r0);
    __syncthreads();
    for (int idx = tid; idx < nr * 96; idx += 256) qs[idx] = q[((size_t)win * NPOS + r0) * 96 + idx];
    for (int mb = 0; mb < 6; mb++) {
      int m0 = mb * 64, mc = min(64, NPOS - m0);
      __syncthreads();
      for (int idx = tid; idx < 96 * 64; idx += 256) {
        int c = idx >> 6, mm = idx & 63;
        kvf[idx] = (mm < mc) ? kT[((size_t)win * CDIM + c) * NPOS + m0 + mm] : 0.f;
      }
      __syncthreads();
      if (lane < mc) {
        float sacc[12];
#pragma unroll
        for (int i = 0; i < 12; i++) sacc[i] = 0.f;
        for (int cq = 0; cq < 24; cq++) {
          float k0 = kvf[(cq * 4 + 0) * 64 + lane];
          float k1 = kvf[(cq * 4 + 1) * 64 + lane];
          float k2 = kvf[(cq * 4 + 2) * 64 + lane];
          float k3 = kvf[(cq * 4 + 3) * 64 + lane];
#pragma unroll
          for (int i = 0; i < 12; i++) {
            int rr = wvi + i * 4;
            float4 q4 = *(const float4*)&qs[rr * 96 + cq * 4];
            sacc[i] += q4.x * k0 + q4.y * k1 + q4.z * k2 + q4.w * k3;
          }
        }
        int m = m0 + lane;
        int ridm = rid[m];
#pragma unroll
        for (int i = 0; i < 12; i++) {
          int rr = wvi + i * 4;
          if (rr < nr) S[rr * 384 + m] = sacc[i] * SCALE + ((rid[r0 + rr] == ridm) ? 0.f : -100.f);
        }
      }
    }
    __syncthreads();
    for (int rr = wvi; rr < nr; rr += 4) {
      float mx = -1e30f;
      for (int m = lane; m < NPOS; m += 64) mx = fmaxf(mx, S[rr * 384 + m]);
#pragma unroll
      for (int d = 32; d; d >>= 1) mx = fmaxf(mx, __shfl_xor(mx, d));
      float pvv[6]; float sum = 0.f; int cnt = 0;
      for (int m = lane; m < NPOS; m += 64) { float e = __expf(S[rr * 384 + m] - mx); pvv[cnt++] = e; sum += e; }
#pragma unroll
      for (int d = 32; d; d >>= 1) sum += __shfl_xor(sum, d);
      float inv = 1.f / sum; cnt = 0;
      for (int m = lane; m < NPOS; m += 64) S[rr * 384 + m] = pvv[cnt++] * inv;
    }
    float acc0[12], acc1[12];
#pragma unroll
    for (int i = 0; i < 12; i++) { acc0[i] = 0.f; acc1[i] = 0.f; }
    for (int vb = 0; vb < 6; vb++) {
      int m0 = vb * 64, mc = min(64, NPOS - m0);
      __syncthreads();
      for (int idx = tid; idx < 64 * 96; idx += 256) {
        int mm = idx / 96, c = idx - mm * 96;
        kvf[idx] = (mm < mc) ? v[((size_t)win * NPOS + m0 + mm) * 96 + c] : 0.f;
      }
      __syncthreads();
      for (int mq = 0; mq < 16; mq++) {
        int mbase = mq * 4;
        float pv0[4], pv1[4];
#pragma unroll
        for (int u = 0; u < 4; u++) {
          pv0[u] = kvf[(mbase + u) * 96 + lane];
          pv1[u] = (lane < 32) ? kvf[(mbase + u) * 96 + 64 + lane] : 0.f;
        }
#pragma unroll
        for (int i = 0; i < 12; i++) {
          int rr = wvi + i * 4;
          float4 p4 = *(const float4*)&S[rr * 384 + m0 + mbase];
          acc0[i] += p4.x * pv0[0] + p4.y * pv0[1] + p4.z * pv0[2] + p4.w * pv0[3];
          acc1[i] += p4.x * pv1[0] + p4.y * pv1[1] + p4.z * pv1[2] + p4.w * pv1[3];
        }
      }
    }
    __syncthreads();  // kvf free -> reuse as out-transpose buffer [96][49]
#pragma unroll
    for (int i = 0; i < 12; i++) {
      int rr = wvi + i * 4;
      if (rr < nr) {
        kvf[lane * 49 + rr] = acc0[i];
        if (lane < 32) kvf[(64 + lane) * 49 + rr] = acc1[i];
      }
    }
    __syncthreads();
    for (int idx = tid; idx < 96 * nr; idx += 256) {
      int cc = idx / nr, r = idx - cc * nr;
      attoutT[((size_t)win * CDIM + cc) * NPOS + r0 + r] = kvf[cc * 49 + r];
    }
  }
}

// ---------------------------------------------------------------- K4: window-reverse + roll(+3) + residual -> xres[n][c]
__global__ __launch_bounds__(256) void k_merge(const float* __restrict__ x,
                                               const float* __restrict__ attoutT,
                                               float* __restrict__ xres) {
  int n0 = blockIdx.x * 64;
  __shared__ float xt[CDIM * 65];
  __shared__ int woff[64];
  int tid = threadIdx.x;
  for (int idx = tid; idx < CDIM * 64; idx += 256) {
    int c = idx >> 6, nn = idx & 63;
    xt[c * 65 + nn] = x[c * NTOT + n0 + nn];
  }
  if (tid < 64) {
    int n = n0 + tid;
    int s = n / 3136, rem = n - s * 3136, h = rem / 56, w = rem - h * 56;
    int a = (s + 53) % 56, b2 = (h + 53) % 56, d2 = (w + 53) % 56;
    int wi = (a / 7) * 64 + (b2 / 7) * 8 + (d2 / 7);
    int nnw = (a % 7) * 49 + (b2 % 7) * 7 + (d2 % 7);
    woff[tid] = wi * (NPOS * CDIM) + nnw * CDIM;
  }
  __syncthreads();
  for (int idx = tid; idx < 64 * 96; idx += 256) {
    int nn = idx / 96, c = idx - nn * 96;
    xres[(size_t)(n0 + nn) * 96 + c] = attoutT[woff[nn] + c] + xt[c * 65 + nn];
  }
}

// ---------------------------------------------------------------- K5: H = gelu(LN2(xres) @ f1w^T + f1b), 128x128 tile, 8x8 micro
// LN2 stats computed in-kernel from the staged tile (no global stats arrays)
__global__ __launch_bounds__(256) void k_mlp1(const float* __restrict__ xres,
                                              const float* __restrict__ n2g, const float* __restrict__ n2b,
                                              const float* __restrict__ f1w, const float* __restrict__ f1b,
                                              float* __restrict__ H, int m_base) {
  __shared__ __attribute__((aligned(16))) float At[96 * 132];
  __shared__ __attribute__((aligned(16))) float Bt[96 * 132];
  __shared__ float mu[128], rs[128];
  int tid = threadIdx.x, ty = tid >> 4, tx = tid & 15;
  int mloc = blockIdx.x * 128, m0g = m_base + mloc, j0 = blockIdx.y * 128;
  for (int idx = tid; idx < 128 * 96; idx += 256) {
    int m = idx / 96, k = idx - m * 96;
    At[k * 132 + m] = xres[(size_t)(m0g + m) * 96 + k];
  }
  for (int idx = tid; idx < 128 * 96; idx += 256) {
    int jj = idx / 96, k = idx - jj * 96;
    Bt[k * 132 + jj] = f1w[(j0 + jj) * 96 + k];
  }
  __syncthreads();
  if (tid < 128) {
    float s = 0.f, s2 = 0.f;
    for (int k = 0; k < 96; k++) { float v = At[k * 132 + tid]; s += v; s2 += v * v; }
    float m = s * (1.f / 96.f);
    float var = s2 * (1.f / 96.f) - m * m;
    mu[tid] = m;
    rs[tid] = 1.f / sqrtf(var + 1e-5f);
  }
  __syncthreads();
  for (int idx = tid; idx < 128 * 96; idx += 256) {
    int m = idx & 127, k = idx >> 7;  // bijective over tile
    At[k * 132 + m] = (At[k * 132 + m] - mu[m]) * rs[m] * n2g[k] + n2b[k];
  }
  __syncthreads();
  float acc[8][8];
#pragma unroll
  for (int i = 0; i < 8; i++)
#pragma unroll
    for (int j = 0; j < 8; j++) acc[i][j] = 0.f;
  for (int k = 0; k < 96; k++) {
    float4 a0 = *(const float4*)&At[k * 132 + 8 * ty];
    float4 a1 = *(const float4*)&At[k * 132 + 8 * ty + 4];
    float4 b0 = *(const float4*)&Bt[k * 132 + 8 * tx];
    float4 b1 = *(const float4*)&Bt[k * 132 + 8 * tx + 4];
    float av[8] = {a0.x, a0.y, a0.z, a0.w, a1.x, a1.y, a1.z, a1.w};
    float bv2[8] = {b0.x, b0.y, b0.z, b0.w, b1.x, b1.y, b1.z, b1.w};
#pragma unroll
    for (int i = 0; i < 8; i++)
#pragma unroll
      for (int j = 0; j < 8; j++) acc[i][j] += av[i] * bv2[j];
  }
#pragma unroll
  for (int i = 0; i < 8; i++) {
#pragma unroll
    for (int j = 0; j < 8; j++) {
      float hh = acc[i][j] + f1b[j0 + 8 * tx + j];
      acc[i][j] = 0.5f * hh * (1.f + erff(hh * 0.7071067811865476f));
    }
    *(float4*)&H[(size_t)(mloc + 8 * ty + i) * HIDD + j0 + 8 * tx]     = *(float4*)&acc[i][0];
    *(float4*)&H[(size_t)(mloc + 8 * ty + i) * HIDD + j0 + 8 * tx + 4] = *(float4*)&acc[i][4];
  }
}

// ---------------------------------------------------------------- K6: out[c][n] = xres + H @ f2w^T + f2b
__global__ __launch_bounds__(256) void k_mlp2(const float* __restrict__ H,
                                              const float* __restrict__ xres,
                                              const float* __restrict__ f2w, const float* __restrict__ f2b,
                                              float* __restrict__ out, int m_base) {
  __shared__ __attribute__((aligned(16))) float At2[96 * 132];
  __shared__ float Bt2[96 * 100];
  int tid = threadIdx.x, ty = tid >> 4, tx = tid & 15;
  int mloc = blockIdx.x * 128, m0g = m_base + mloc;
  float acc[8][6];
#pragma unroll
  for (int i = 0; i < 8; i++)
#pragma unroll
    for (int j = 0; j < 6; j++) acc[i][j] = 0.f;
  for (int kb = 0; kb < HIDD; kb += 96) {
    __syncthreads();
    for (int idx = tid; idx < 128 * 96; idx += 256) {
      int m = idx / 96, k = idx - m * 96;
      At2[k * 132 + m] = H[(size_t)(mloc + m) * HIDD + kb + k];
    }
    for (int idx = tid; idx < 96 * 96; idx += 256) {
      int c = idx / 96, k = idx - c * 96;
      Bt2[k * 100 + c] = f2w[c * HIDD + kb + k];
    }
    __syncthreads();
    for (int k = 0; k < 96; k++) {
      float4 a0 = *(const float4*)&At2[k * 132 + 8 * ty];
      float4 a1 = *(const float4*)&At2[k * 132 + 8 * ty + 4];
      float av[8] = {a0.x, a0.y, a0.z, a0.w, a1.x, a1.y, a1.z, a1.w};
      float bv2[6];
#pragma unroll
      for (int j = 0; j < 6; j++) bv2[j] = Bt2[k * 100 + 6 * tx + j];
#pragma unroll
      for (int i = 0; i < 8; i++)
#pragma unroll
        for (int j = 0; j < 6; j++) acc[i][j] += av[i] * bv2[j];
    }
  }
#pragma unroll
  for (int i = 0; i < 8; i++)
#pragma unroll
    for (int j = 0; j < 6; j++) {
      int n = m0g + 8 * ty + i, c = 6 * tx + j;
      out[(size_t)c * NTOT + n] = acc[i][j] + f2b[c] + xres[(size_t)n * 96 + c];
    }
}

// ----------------------------------------------------------------
extern "C" void kernel_launch(void* const* d_in, const int* in_sizes, int n_in,
                              void* d_out, int out_size, void* d_ws, size_t ws_size,
                              hipStream_t stream) {
  const float* x   = (const float*)d_in[0];
  const float* n1g = (const float*)d_in[1];
  const float* n1b = (const float*)d_in[2];
  const float* wq  = (const float*)d_in[3];
  const float* bq  = (const float*)d_in[4];
  const float* wk  = (const float*)d_in[5];
  const float* bk  = (const float*)d_in[6];
  const float* wv  = (const float*)d_in[7];
  const float* bv  = (const float*)d_in[8];
  const float* dqw = (const float*)d_in[9];
  const float* dqb = (const float*)d_in[10];
  const float* dkw = (const float*)d_in[11];
  const float* dkb = (const float*)d_in[12];
  const float* dvw = (const float*)d_in[13];
  const float* dvb = (const float*)d_in[14];
  const float* n2g = (const float*)d_in[15];
  const float* n2b = (const float*)d_in[16];
  const float* f1w = (const float*)d_in[17];
  const float* f1b = (const float*)d_in[18];
  const float* f2w = (const float*)d_in[19];
  const float* f2b = (const float*)d_in[20];
  float* out = (float*)d_out;
  float* ws = (float*)d_ws;

  const size_t need = (size_t)3 * SLOT * 4;
  if (ws_size < need) {
    fprintf(stderr, "kernel_launch: ws_size %zu < needed %zu -- aborting launch\n", ws_size, need);
    return;
  }

  // slot A: Xw (K1->K2), then attoutT (K3->K4)
  // slot B: q  (K2->K3), then xres    (K4->K6)
  // slot C: v  (K2->K3), then H chunk (K5->K6), NTOT/4 rows = exactly 1 SLOT
  // d_out : kT (K2->K3), then final output (K6)
  float* Xw      = ws;
  float* attoutT = ws;
  float* qbuf    = ws + (size_t)SLOT;
  float* xres    = ws + (size_t)SLOT;
  float* vbuf    = ws + (size_t)2 * SLOT;
  float* Hbuf    = ws + (size_t)2 * SLOT;
  float* kTbuf   = out;

  k_ln1<<<dim3(NWIN, 6), 256, 0, stream>>>(x, n1g, n1b, Xw);
  k_qkv<<<dim3(NWIN, 3, 3), 256, 0, stream>>>(Xw, wq, bq, dqw, dqb, wk, bk, dkw, dkb,
                                              wv, bv, dvw, dvb, qbuf, kTbuf, vbuf);
  k_attn<<<NWIN, 256, 0, stream>>>(qbuf, kTbuf, vbuf, attoutT);
  k_merge<<<NTOT / 64, 256, 0, stream>>>(x, attoutT, xres);
  for (int ch = 0; ch < 4; ch++) {
    int m_base = ch * (NTOT / 4);
    k_mlp1<<<dim3(NTOT / 4 / 128, 3), 256, 0, stream>>>(xres, n2g, n2b, f1w, f1b, Hbuf, m_base);
    k_mlp2<<<NTOT / 4 / 128, 256, 0, stream>>>(Hbuf, xres, f2w, f2b, out, m_base);
  }
}

// Round 6
// 2628.112 us; speedup vs baseline: 1.9496x; 1.9496x over previous
//
#include <hip/hip_runtime.h>
#include <cstdio>

#define NTOT 175616   // 56^3
#define CDIM 96
#define NPOS 343      // 7^3
#define NWIN 512      // 8^3
#define HIDD 384
#define SLOT 16859136 // NWIN*CDIM*NPOS = NTOT*CDIM
#define SCALE 0.10206207261596577f  // 1/sqrt(96)

typedef __attribute__((ext_vector_type(8))) short short8;
typedef __attribute__((ext_vector_type(4))) float f32x4;

__device__ inline ushort f2bf(float f) {
  union { float f; unsigned u; } v; v.f = f;
  unsigned r = v.u + 0x7FFFu + ((v.u >> 16) & 1u);
  return (ushort)(r >> 16);
}

// ---------------------------------------------------------------- K1: LN1 + roll(-3) + window partition -> Xw[win][c][p]
__global__ __launch_bounds__(256) void k_ln1(const float* __restrict__ x,
                                             const float* __restrict__ g,
                                             const float* __restrict__ b,
                                             float* __restrict__ Xw) {
  int win = blockIdx.x;
  int p0 = blockIdx.y * 64;
  int cnt = min(64, NPOS - p0);
  int wz = win >> 6, wy = (win >> 3) & 7, wx = win & 7;
  __shared__ float raw[CDIM][64];
  __shared__ float psum[4][64], psq[4][64];
  __shared__ float mean[64], rstd[64];
  int tid = threadIdx.x;
  for (int idx = tid; idx < CDIM * 64; idx += 256) {
    int c = idx >> 6, pp = idx & 63;
    float v = 0.f;
    if (pp < cnt) {
      int p = p0 + pp;
      int lz = p / 49, ly = (p / 7) % 7, lx = p % 7;
      int s = (wz * 7 + lz + 3) % 56;
      int h = (wy * 7 + ly + 3) % 56;
      int w = (wx * 7 + lx + 3) % 56;
      v = x[c * NTOT + (s * 3136 + h * 56 + w)];
    }
    raw[c][pp] = v;
  }
  __syncthreads();
  {
    int pp = tid & 63, grp = tid >> 6;
    float s = 0.f, s2 = 0.f;
    for (int i = 0; i < 24; i++) { float v = raw[grp * 24 + i][pp]; s += v; s2 += v * v; }
    psum[grp][pp] = s; psq[grp][pp] = s2;
  }
  __syncthreads();
  if (tid < 64) {
    float s = psum[0][tid] + psum[1][tid] + psum[2][tid] + psum[3][tid];
    float s2 = psq[0][tid] + psq[1][tid] + psq[2][tid] + psq[3][tid];
    float m = s * (1.f / 96.f);
    float var = s2 * (1.f / 96.f) - m * m;
    mean[tid] = m;
    rstd[tid] = 1.f / sqrtf(var + 1e-5f);
  }
  __syncthreads();
  for (int idx = tid; idx < CDIM * 64; idx += 256) {
    int c = idx >> 6, pp = idx & 63;
    if (pp < cnt) {
      float v = (raw[c][pp] - mean[pp]) * rstd[pp] * g[c] + b[c];
      Xw[(win * CDIM + c) * NPOS + p0 + pp] = v;
    }
  }
}

// ---------------------------------------------------------------- K2: conv1x1 (GEMM) + depthwise 3x3x3 per window
__global__ __launch_bounds__(256) void k_qkv(
    const float* __restrict__ Xw,
    const float* __restrict__ wq, const float* __restrict__ bq, const float* __restrict__ dqw, const float* __restrict__ dqb,
    const float* __restrict__ wk, const float* __restrict__ bk, const float* __restrict__ dkw, const float* __restrict__ dkb,
    const float* __restrict__ wv, const float* __restrict__ bv, const float* __restrict__ dvw, const float* __restrict__ dvb,
    float* __restrict__ qo, float* __restrict__ kTo, float* __restrict__ vo) {
  int win = blockIdx.x, t = blockIdx.y, ob = blockIdx.z * 32;
  const float *W, *B, *DW, *DB; float* O; bool pfast;
  if (t == 0)      { W = wq; B = bq; DW = dqw; DB = dqb; O = qo;  pfast = false; }
  else if (t == 1) { W = wk; B = bk; DW = dkw; DB = dkb; O = kTo; pfast = true;  }
  else             { W = wv; B = bv; DW = dvw; DB = dvb; O = vo;  pfast = false; }
  __shared__ float wA[32][96];
  __shared__ float dwl[32][27];
  __shared__ float tl[32][345];
  int tid = threadIdx.x, lane = tid & 63, wvi = tid >> 6;
  for (int idx = tid; idx < 32 * 96; idx += 256) wA[idx / 96][idx % 96] = W[(ob + idx / 96) * 96 + idx % 96];
  for (int idx = tid; idx < 32 * 27; idx += 256) dwl[idx / 27][idx % 27] = DW[(ob + idx / 27) * 27 + idx % 27];
  __syncthreads();
  const float* xp = Xw + (size_t)win * CDIM * NPOS;
  for (int pb2 = 0; pb2 < 6; pb2++) {
    int p = pb2 * 64 + lane;
    if (p < NPOS) {
      float acc[8];
#pragma unroll
      for (int i = 0; i < 8; i++) acc[i] = B[ob + wvi * 8 + i];
      for (int c = 0; c < 96; c++) {
        float xv = xp[c * NPOS + p];
#pragma unroll
        for (int i = 0; i < 8; i++) acc[i] += wA[wvi * 8 + i][c] * xv;
      }
#pragma unroll
      for (int i = 0; i < 8; i++) tl[wvi * 8 + i][p] = acc[i];
    }
  }
  __syncthreads();
  for (int idx = tid; idx < 32 * NPOS; idx += 256) {
    int o, p;
    if (pfast) { o = idx / NPOS; p = idx - o * NPOS; }
    else       { o = idx & 31;  p = idx >> 5; }
    int lz = p / 49, r1 = p - lz * 49, ly = r1 / 7, lx = r1 - ly * 7;
    float acc = DB[ob + o];
    for (int dz = -1; dz <= 1; dz++) {
      int z = lz + dz; if ((unsigned)z >= 7u) continue;
      for (int dy = -1; dy <= 1; dy++) {
        int y = ly + dy; if ((unsigned)y >= 7u) continue;
        for (int dx = -1; dx <= 1; dx++) {
          int xx = lx + dx; if ((unsigned)xx >= 7u) continue;
          acc += dwl[o][(dz + 1) * 9 + (dy + 1) * 3 + (dx + 1)] * tl[o][z * 49 + y * 7 + xx];
        }
      }
    }
    if (pfast) O[((size_t)win * CDIM + ob + o) * NPOS + p] = acc;
    else       O[((size_t)win * NPOS + p) * CDIM + ob + o] = acc;
  }
}

// ---------------------------------------------------------------- K3: windowed attention via MFMA bf16 (fp32 softmax/accum)
// writes attoutT[win][c][r]  (equals the torch axis-mixing trick when read flat)
#define KSTR 104   // kb row stride (shorts): 16B-multiple, 2-way bank alias (free)
#define VSTR 200   // vb row stride (shorts)
#define PSTR 360   // pb row stride (shorts)
__global__ __launch_bounds__(256) void k_attn(const float* __restrict__ q,
                                              const float* __restrict__ kT,
                                              const float* __restrict__ v,
                                              float* __restrict__ attoutT) {
  int win = blockIdx.x;
  int wz = win >> 6, wy = (win >> 3) & 7, wx = win & 7;
  __shared__ __attribute__((aligned(16))) ushort kb[352 * KSTR];      // K[m][c] bf16, full
  __shared__ __attribute__((aligned(16))) ushort vb[96 * VSTR];       // V^T[c][mloc] bf16, half-streamed
  __shared__ __attribute__((aligned(16))) ushort pb[4][16 * PSTR];    // per-wave P[r][m] bf16
  __shared__ int rid[344];
  int tid = threadIdx.x, lane = tid & 63, wid = tid >> 6;

  // region ids in rolled coords
  for (int p = tid; p < NPOS; p += 256) {
    int lz = p / 49, r1 = p - lz * 49, ly = r1 / 7, lx = r1 - ly * 7;
    int az = wz * 7 + lz, ay = wy * 7 + ly, ax = wx * 7 + lx;
    int rz = (az < 49) ? 0 : ((az < 53) ? 1 : 2);
    int ry = (ay < 49) ? 0 : ((ay < 53) ? 1 : 2);
    int rx = (ax < 49) ? 0 : ((ax < 53) ? 1 : 2);
    rid[p] = rz * 9 + ry * 3 + rx;
  }
  // stage K once: kT[win][c][m] fp32 -> kb[m][c] bf16 (pad m>=343 with 0)
  {
    const float* kp = kT + (size_t)win * CDIM * NPOS;
    for (int c = (tid >> 6); c < 96; c += 4) {
      for (int m = lane; m < 352; m += 64) {
        float val = (m < NPOS) ? kp[c * NPOS + m] : 0.f;
        kb[m * KSTR + c] = f2bf(val);
      }
    }
  }
  __syncthreads();

  const float* qp = q + (size_t)win * NPOS * CDIM;
  const float* vp = v + (size_t)win * NPOS * CDIM;
  int mcol = lane & 15;
  int grp  = lane >> 4;
  int cb   = grp * 8;

  for (int iter = 0; iter < 6; ++iter) {
    int t = iter * 4 + wid;
    bool valid = t < 22;
    int r0 = t * 16;
    f32x4 oacc[6];
    if (valid) {
      // ---- Q fragments (A-layout: row=lane&15, k=grp*8+e), fp32->bf16
      short8 aq[3];
      int r = r0 + mcol;
      int rl = (r < NPOS) ? r : (NPOS - 1);
#pragma unroll
      for (int kc = 0; kc < 3; ++kc) {
        const float* src = qp + (size_t)rl * 96 + kc * 32 + cb;
        float4 f0 = *(const float4*)(src);
        float4 f1 = *(const float4*)(src + 4);
        short8 a;
        a[0] = (short)f2bf(f0.x); a[1] = (short)f2bf(f0.y); a[2] = (short)f2bf(f0.z); a[3] = (short)f2bf(f0.w);
        a[4] = (short)f2bf(f1.x); a[5] = (short)f2bf(f1.y); a[6] = (short)f2bf(f1.z); a[7] = (short)f2bf(f1.w);
        aq[kc] = a;
      }
      // ---- S = Q K^T in registers (22 m-tiles x 3 k-chunks)
      f32x4 sacc[22];
#pragma unroll
      for (int mf = 0; mf < 22; ++mf) {
        f32x4 acc = {0.f, 0.f, 0.f, 0.f};
#pragma unroll
        for (int kc = 0; kc < 3; ++kc) {
          short8 bfr = *(const short8*)&kb[(mf * 16 + mcol) * KSTR + kc * 32 + cb];
          acc = __builtin_amdgcn_mfma_f32_16x16x32_bf16(aq[kc], bfr, acc, 0, 0, 0);
        }
        sacc[mf] = acc;
      }
      // ---- mask + wave-local softmax (C-layout: col=lane&15, row=grp*4+j)
      int ridr[4];
#pragma unroll
      for (int j = 0; j < 4; ++j) {
        int rr = r0 + grp * 4 + j;
        ridr[j] = (rr < NPOS) ? rid[rr] : -2;
      }
#pragma unroll
      for (int mf = 0; mf < 22; ++mf) {
        int m = mf * 16 + mcol;
        int ridm = (m < NPOS) ? rid[m] : -1;
#pragma unroll
        for (int j = 0; j < 4; ++j)
          sacc[mf][j] = sacc[mf][j] * SCALE + ((ridm == ridr[j]) ? 0.f : -100.f);
      }
      float mx[4] = {-1e30f, -1e30f, -1e30f, -1e30f};
#pragma unroll
      for (int mf = 0; mf < 22; ++mf)
#pragma unroll
        for (int j = 0; j < 4; ++j) mx[j] = fmaxf(mx[j], sacc[mf][j]);
#pragma unroll
      for (int d = 1; d < 16; d <<= 1)
#pragma unroll
        for (int j = 0; j < 4; ++j) mx[j] = fmaxf(mx[j], __shfl_xor(mx[j], d));
      float sum[4] = {0.f, 0.f, 0.f, 0.f};
#pragma unroll
      for (int mf = 0; mf < 22; ++mf)
#pragma unroll
        for (int j = 0; j < 4; ++j) { float e = __expf(sacc[mf][j] - mx[j]); sacc[mf][j] = e; sum[j] += e; }
#pragma unroll
      for (int d = 1; d < 16; d <<= 1)
#pragma unroll
        for (int j = 0; j < 4; ++j) sum[j] += __shfl_xor(sum[j], d);
      float inv[4];
#pragma unroll
      for (int j = 0; j < 4; ++j) inv[j] = 1.f / sum[j];
      // ---- P -> own LDS slice, bf16, [r][m]
      ushort* pp = pb[wid];
#pragma unroll
      for (int mf = 0; mf < 22; ++mf) {
        int m = mf * 16 + mcol;
#pragma unroll
        for (int j = 0; j < 4; ++j)
          pp[(grp * 4 + j) * PSTR + m] = f2bf(sacc[mf][j] * inv[j]);
      }
      asm volatile("s_waitcnt lgkmcnt(0)" ::: "memory");  // own-wave cross-lane LDS visibility
    }
    __syncthreads();
    // ---- V half 1 (m 0..191): v[m][c] fp32 -> vb[c][mloc] bf16
    for (int idx = tid; idx < 192 * 24; idx += 256) {
      int mloc = idx / 24, cq = idx - mloc * 24;
      float4 f = make_float4(0.f, 0.f, 0.f, 0.f);
      if (mloc < NPOS) f = *(const float4*)(vp + (size_t)mloc * 96 + cq * 4);
      vb[(cq * 4 + 0) * VSTR + mloc] = f2bf(f.x);
      vb[(cq * 4 + 1) * VSTR + mloc] = f2bf(f.y);
      vb[(cq * 4 + 2) * VSTR + mloc] = f2bf(f.z);
      vb[(cq * 4 + 3) * VSTR + mloc] = f2bf(f.w);
    }
    __syncthreads();
    if (valid) {
#pragma unroll
      for (int cf = 0; cf < 6; ++cf) oacc[cf] = f32x4{0.f, 0.f, 0.f, 0.f};
      const ushort* pp = pb[wid];
#pragma unroll
      for (int kc = 0; kc < 6; ++kc) {
        short8 a = *(const short8*)&pp[mcol * PSTR + kc * 32 + cb];
#pragma unroll
        for (int cf = 0; cf < 6; ++cf) {
          short8 bfr = *(const short8*)&vb[(cf * 16 + mcol) * VSTR + kc * 32 + cb];
          oacc[cf] = __builtin_amdgcn_mfma_f32_16x16x32_bf16(a, bfr, oacc[cf], 0, 0, 0);
        }
      }
    }
    __syncthreads();
    // ---- V half 2 (m 192..351)
    for (int idx = tid; idx < 160 * 24; idx += 256) {
      int mloc = idx / 24, cq = idx - mloc * 24;
      int m = 192 + mloc;
      float4 f = make_float4(0.f, 0.f, 0.f, 0.f);
      if (m < NPOS) f = *(const float4*)(vp + (size_t)m * 96 + cq * 4);
      vb[(cq * 4 + 0) * VSTR + mloc] = f2bf(f.x);
      vb[(cq * 4 + 1) * VSTR + mloc] = f2bf(f.y);
      vb[(cq * 4 + 2) * VSTR + mloc] = f2bf(f.z);
      vb[(cq * 4 + 3) * VSTR + mloc] = f2bf(f.w);
    }
    __syncthreads();
    if (valid) {
      const ushort* pp = pb[wid];
#pragma unroll
      for (int kc = 0; kc < 5; ++kc) {
        short8 a = *(const short8*)&pp[mcol * PSTR + 192 + kc * 32 + cb];
#pragma unroll
        for (int cf = 0; cf < 6; ++cf) {
          short8 bfr = *(const short8*)&vb[(cf * 16 + mcol) * VSTR + kc * 32 + cb];
          oacc[cf] = __builtin_amdgcn_mfma_f32_16x16x32_bf16(a, bfr, oacc[cf], 0, 0, 0);
        }
      }
      // ---- store O: D col=lane&15 -> channel, rows grp*4+j -> r
#pragma unroll
      for (int cf = 0; cf < 6; ++cf) {
        int c = cf * 16 + mcol;
#pragma unroll
        for (int j = 0; j < 4; ++j) {
          int r = r0 + grp * 4 + j;
          if (r < NPOS) attoutT[((size_t)win * CDIM + c) * NPOS + r] = oacc[cf][j];
        }
      }
    }
  }
}

// ---------------------------------------------------------------- K4: window-reverse + roll(+3) + residual -> xres[n][c]
__global__ __launch_bounds__(256) void k_merge(const float* __restrict__ x,
                                               const float* __restrict__ attoutT,
                                               float* __restrict__ xres) {
  int n0 = blockIdx.x * 64;
  __shared__ float xt[CDIM * 65];
  __shared__ int woff[64];
  int tid = threadIdx.x;
  for (int idx = tid; idx < CDIM * 64; idx += 256) {
    int c = idx >> 6, nn = idx & 63;
    xt[c * 65 + nn] = x[c * NTOT + n0 + nn];
  }
  if (tid < 64) {
    int n = n0 + tid;
    int s = n / 3136, rem = n - s * 3136, h = rem / 56, w = rem - h * 56;
    int a = (s + 53) % 56, b2 = (h + 53) % 56, d2 = (w + 53) % 56;
    int wi = (a / 7) * 64 + (b2 / 7) * 8 + (d2 / 7);
    int nnw = (a % 7) * 49 + (b2 % 7) * 7 + (d2 % 7);
    woff[tid] = wi * (NPOS * CDIM) + nnw * CDIM;
  }
  __syncthreads();
  for (int idx = tid; idx < 64 * 96; idx += 256) {
    int nn = idx / 96, c = idx - nn * 96;
    xres[(size_t)(n0 + nn) * 96 + c] = attoutT[woff[nn] + c] + xt[c * 65 + nn];
  }
}

// ---------------------------------------------------------------- K5: H = gelu(LN2(xres) @ f1w^T + f1b)
__global__ __launch_bounds__(256) void k_mlp1(const float* __restrict__ xres,
                                              const float* __restrict__ n2g, const float* __restrict__ n2b,
                                              const float* __restrict__ f1w, const float* __restrict__ f1b,
                                              float* __restrict__ H, int m_base) {
  __shared__ __attribute__((aligned(16))) float At[96 * 132];
  __shared__ __attribute__((aligned(16))) float Bt[96 * 132];
  __shared__ float mu[128], rs[128];
  int tid = threadIdx.x, ty = tid >> 4, tx = tid & 15;
  int mloc = blockIdx.x * 128, m0g = m_base + mloc, j0 = blockIdx.y * 128;
  for (int idx = tid; idx < 128 * 96; idx += 256) {
    int m = idx / 96, k = idx - m * 96;
    At[k * 132 + m] = xres[(size_t)(m0g + m) * 96 + k];
  }
  for (int idx = tid; idx < 128 * 96; idx += 256) {
    int jj = idx / 96, k = idx - jj * 96;
    Bt[k * 132 + jj] = f1w[(j0 + jj) * 96 + k];
  }
  __syncthreads();
  if (tid < 128) {
    float s = 0.f, s2 = 0.f;
    for (int k = 0; k < 96; k++) { float v = At[k * 132 + tid]; s += v; s2 += v * v; }
    float m = s * (1.f / 96.f);
    float var = s2 * (1.f / 96.f) - m * m;
    mu[tid] = m;
    rs[tid] = 1.f / sqrtf(var + 1e-5f);
  }
  __syncthreads();
  for (int idx = tid; idx < 128 * 96; idx += 256) {
    int m = idx & 127, k = idx >> 7;
    At[k * 132 + m] = (At[k * 132 + m] - mu[m]) * rs[m] * n2g[k] + n2b[k];
  }
  __syncthreads();
  float acc[8][8];
#pragma unroll
  for (int i = 0; i < 8; i++)
#pragma unroll
    for (int j = 0; j < 8; j++) acc[i][j] = 0.f;
  for (int k = 0; k < 96; k++) {
    float4 a0 = *(const float4*)&At[k * 132 + 8 * ty];
    float4 a1 = *(const float4*)&At[k * 132 + 8 * ty + 4];
    float4 b0 = *(const float4*)&Bt[k * 132 + 8 * tx];
    float4 b1 = *(const float4*)&Bt[k * 132 + 8 * tx + 4];
    float av[8] = {a0.x, a0.y, a0.z, a0.w, a1.x, a1.y, a1.z, a1.w};
    float bv2[8] = {b0.x, b0.y, b0.z, b0.w, b1.x, b1.y, b1.z, b1.w};
#pragma unroll
    for (int i = 0; i < 8; i++)
#pragma unroll
      for (int j = 0; j < 8; j++) acc[i][j] += av[i] * bv2[j];
  }
#pragma unroll
  for (int i = 0; i < 8; i++) {
#pragma unroll
    for (int j = 0; j < 8; j++) {
      float hh = acc[i][j] + f1b[j0 + 8 * tx + j];
      acc[i][j] = 0.5f * hh * (1.f + erff(hh * 0.7071067811865476f));
    }
    *(float4*)&H[(size_t)(mloc + 8 * ty + i) * HIDD + j0 + 8 * tx]     = *(float4*)&acc[i][0];
    *(float4*)&H[(size_t)(mloc + 8 * ty + i) * HIDD + j0 + 8 * tx + 4] = *(float4*)&acc[i][4];
  }
}

// ---------------------------------------------------------------- K6: out[c][n] = xres + H @ f2w^T + f2b
__global__ __launch_bounds__(256) void k_mlp2(const float* __restrict__ H,
                                              const float* __restrict__ xres,
                                              const float* __restrict__ f2w, const float* __restrict__ f2b,
                                              float* __restrict__ out, int m_base) {
  __shared__ __attribute__((aligned(16))) float At2[96 * 132];
  __shared__ float Bt2[96 * 100];
  int tid = threadIdx.x, ty = tid >> 4, tx = tid & 15;
  int mloc = blockIdx.x * 128, m0g = m_base + mloc;
  float acc[8][6];
#pragma unroll
  for (int i = 0; i < 8; i++)
#pragma unroll
    for (int j = 0; j < 6; j++) acc[i][j] = 0.f;
  for (int kb2 = 0; kb2 < HIDD; kb2 += 96) {
    __syncthreads();
    for (int idx = tid; idx < 128 * 96; idx += 256) {
      int m = idx / 96, k = idx - m * 96;
      At2[k * 132 + m] = H[(size_t)(mloc + m) * HIDD + kb2 + k];
    }
    for (int idx = tid; idx < 96 * 96; idx += 256) {
      int c = idx / 96, k = idx - c * 96;
      Bt2[k * 100 + c] = f2w[c * HIDD + kb2 + k];
    }
    __syncthreads();
    for (int k = 0; k < 96; k++) {
      float4 a0 = *(const float4*)&At2[k * 132 + 8 * ty];
      float4 a1 = *(const float4*)&At2[k * 132 + 8 * ty + 4];
      float av[8] = {a0.x, a0.y, a0.z, a0.w, a1.x, a1.y, a1.z, a1.w};
      float bv2[6];
#pragma unroll
      for (int j = 0; j < 6; j++) bv2[j] = Bt2[k * 100 + 6 * tx + j];
#pragma unroll
      for (int i = 0; i < 8; i++)
#pragma unroll
        for (int j = 0; j < 6; j++) acc[i][j] += av[i] * bv2[j];
    }
  }
#pragma unroll
  for (int i = 0; i < 8; i++)
#pragma unroll
    for (int j = 0; j < 6; j++) {
      int n = m0g + 8 * ty + i, c = 6 * tx + j;
      out[(size_t)c * NTOT + n] = acc[i][j] + f2b[c] + xres[(size_t)n * 96 + c];
    }
}

// ----------------------------------------------------------------
extern "C" void kernel_launch(void* const* d_in, const int* in_sizes, int n_in,
                              void* d_out, int out_size, void* d_ws, size_t ws_size,
                              hipStream_t stream) {
  const float* x   = (const float*)d_in[0];
  const float* n1g = (const float*)d_in[1];
  const float* n1b = (const float*)d_in[2];
  const float* wq  = (const float*)d_in[3];
  const float* bq  = (const float*)d_in[4];
  const float* wk  = (const float*)d_in[5];
  const float* bk  = (const float*)d_in[6];
  const float* wv  = (const float*)d_in[7];
  const float* bv  = (const float*)d_in[8];
  const float* dqw = (const float*)d_in[9];
  const float* dqb = (const float*)d_in[10];
  const float* dkw = (const float*)d_in[11];
  const float* dkb = (const float*)d_in[12];
  const float* dvw = (const float*)d_in[13];
  const float* dvb = (const float*)d_in[14];
  const float* n2g = (const float*)d_in[15];
  const float* n2b = (const float*)d_in[16];
  const float* f1w = (const float*)d_in[17];
  const float* f1b = (const float*)d_in[18];
  const float* f2w = (const float*)d_in[19];
  const float* f2b = (const float*)d_in[20];
  float* out = (float*)d_out;
  float* ws = (float*)d_ws;

  const size_t need = (size_t)3 * SLOT * 4;
  if (ws_size < need) {
    fprintf(stderr, "kernel_launch: ws_size %zu < needed %zu -- aborting launch\n", ws_size, need);
    return;
  }

  // slot A: Xw (K1->K2), then attoutT (K3->K4)
  // slot B: q  (K2->K3), then xres    (K4->K6)
  // slot C: v  (K2->K3), then H chunk (K5->K6)
  // d_out : kT (K2->K3), then final output (K6)
  float* Xw      = ws;
  float* attoutT = ws;
  float* qbuf    = ws + (size_t)SLOT;
  float* xres    = ws + (size_t)SLOT;
  float* vbuf    = ws + (size_t)2 * SLOT;
  float* Hbuf    = ws + (size_t)2 * SLOT;
  float* kTbuf   = out;

  k_ln1<<<dim3(NWIN, 6), 256, 0, stream>>>(x, n1g, n1b, Xw);
  k_qkv<<<dim3(NWIN, 3, 3), 256, 0, stream>>>(Xw, wq, bq, dqw, dqb, wk, bk, dkw, dkb,
                                              wv, bv, dvw, dvb, qbuf, kTbuf, vbuf);
  k_attn<<<NWIN, 256, 0, stream>>>(qbuf, kTbuf, vbuf, attoutT);
  k_merge<<<NTOT / 64, 256, 0, stream>>>(x, attoutT, xres);
  for (int ch = 0; ch < 4; ch++) {
    int m_base = ch * (NTOT / 4);
    k_mlp1<<<dim3(NTOT / 4 / 128, 3), 256, 0, stream>>>(xres, n2g, n2b, f1w, f1b, Hbuf, m_base);
    k_mlp2<<<NTOT / 4 / 128, 256, 0, stream>>>(Hbuf, xres, f2w, f2b, out, m_base);
  }
}

// Round 8
// 1580.095 us; speedup vs baseline: 3.2427x; 1.6633x over previous
//
#include <hip/hip_runtime.h>
#include <cstdio>

#define NTOT 175616   // 56^3
#define CDIM 96
#define NPOS 343      // 7^3
#define NWIN 512      // 8^3
#define HIDD 384
#define SLOT 16859136 // NWIN*CDIM*NPOS = NTOT*CDIM
#define SCALE 0.10206207261596577f  // 1/sqrt(96)

typedef __attribute__((ext_vector_type(8))) short short8;
typedef __attribute__((ext_vector_type(4))) float f32x4;

__device__ inline ushort f2bf(float f) {
  union { float f; unsigned u; } v; v.f = f;
  unsigned r = v.u + 0x7FFFu + ((v.u >> 16) & 1u);
  return (ushort)(r >> 16);
}

// ---------------------------------------------------------------- K1: LN1 + roll(-3) + window partition -> Xw[win][p][c] bf16
__global__ __launch_bounds__(256) void k_ln1(const float* __restrict__ x,
                                             const float* __restrict__ g,
                                             const float* __restrict__ b,
                                             ushort* __restrict__ Xw) {
  int win = blockIdx.x;
  int p0 = blockIdx.y * 64;
  int cnt = min(64, NPOS - p0);
  int wz = win >> 6, wy = (win >> 3) & 7, wx = win & 7;
  __shared__ float raw[CDIM][65];
  __shared__ float psum[4][64], psq[4][64];
  __shared__ float mean[64], rstd[64];
  int tid = threadIdx.x;
  for (int idx = tid; idx < CDIM * 64; idx += 256) {
    int c = idx >> 6, pp = idx & 63;
    float v = 0.f;
    if (pp < cnt) {
      int p = p0 + pp;
      int lz = p / 49, ly = (p / 7) % 7, lx = p % 7;
      int s = (wz * 7 + lz + 3) % 56;
      int h = (wy * 7 + ly + 3) % 56;
      int w = (wx * 7 + lx + 3) % 56;
      v = x[c * NTOT + (s * 3136 + h * 56 + w)];
    }
    raw[c][pp] = v;
  }
  __syncthreads();
  {
    int pp = tid & 63, grp = tid >> 6;
    float s = 0.f, s2 = 0.f;
    for (int i = 0; i < 24; i++) { float v = raw[grp * 24 + i][pp]; s += v; s2 += v * v; }
    psum[grp][pp] = s; psq[grp][pp] = s2;
  }
  __syncthreads();
  if (tid < 64) {
    float s = psum[0][tid] + psum[1][tid] + psum[2][tid] + psum[3][tid];
    float s2 = psq[0][tid] + psq[1][tid] + psq[2][tid] + psq[3][tid];
    float m = s * (1.f / 96.f);
    float var = s2 * (1.f / 96.f) - m * m;
    mean[tid] = m;
    rstd[tid] = 1.f / sqrtf(var + 1e-5f);
  }
  __syncthreads();
  for (int idx = tid; idx < cnt * 96; idx += 256) {
    int pp = idx / 96, c = idx - pp * 96;
    float v = (raw[c][pp] - mean[pp]) * rstd[pp] * g[c] + b[c];
    Xw[((size_t)win * NPOS + p0 + pp) * 96 + c] = f2bf(v);
  }
}

// ---------------------------------------------------------------- K2: MFMA conv1x1 + depthwise 3x3x3 per window
// grid (win, tensor, half): block computes 48 output channels [ob, ob+48)
// outputs q/k/v all as [win][p][c] bf16
__global__ __launch_bounds__(256) void k_qkv(
    const ushort* __restrict__ Xw,
    const float* __restrict__ wq, const float* __restrict__ bq, const float* __restrict__ dqw, const float* __restrict__ dqb,
    const float* __restrict__ wk, const float* __restrict__ bk, const float* __restrict__ dkw, const float* __restrict__ dkb,
    const float* __restrict__ wv, const float* __restrict__ bv, const float* __restrict__ dvw, const float* __restrict__ dvb,
    ushort* __restrict__ qo, ushort* __restrict__ ko, ushort* __restrict__ vo) {
  int win = blockIdx.x, t = blockIdx.y, ob = blockIdx.z * 48;
  const float *W, *B, *DW, *DB; ushort* O;
  if (t == 0)      { W = wq; B = bq; DW = dqw; DB = dqb; O = qo; }
  else if (t == 1) { W = wk; B = bk; DW = dkw; DB = dkb; O = ko; }
  else             { W = wv; B = bv; DW = dvw; DB = dvb; O = vo; }
  __shared__ __attribute__((aligned(16))) float tl[48 * 353];   // conv1x1 out [olocal][p]
  __shared__ float dwl[48][27];
  int tid = threadIdx.x, lane = tid & 63, wid = tid >> 6;
  int mcol = lane & 15, grp = lane >> 4;

  for (int idx = tid; idx < 48 * 27; idx += 256)
    dwl[idx / 27][idx % 27] = DW[(ob + idx / 27) * 27 + idx % 27];

  // ---- B fragments (weights) + bias, register-resident per wave
  short8 bfr[3][3];
  float bias_n[3];
#pragma unroll
  for (int n = 0; n < 3; ++n) {
    int o = ob + n * 16 + mcol;
    bias_n[n] = B[o];
#pragma unroll
    for (int kc = 0; kc < 3; ++kc) {
      const float* src = W + (size_t)o * 96 + kc * 32 + grp * 8;
      float4 f0 = *(const float4*)(src);
      float4 f1 = *(const float4*)(src + 4);
      short8 a;
      a[0] = (short)f2bf(f0.x); a[1] = (short)f2bf(f0.y); a[2] = (short)f2bf(f0.z); a[3] = (short)f2bf(f0.w);
      a[4] = (short)f2bf(f1.x); a[5] = (short)f2bf(f1.y); a[6] = (short)f2bf(f1.z); a[7] = (short)f2bf(f1.w);
      bfr[n][kc] = a;
    }
  }
  // ---- GEMM: tl[o][p] = sum_c Xw[p][c] * W[o][c] + bias
  const ushort* xp = Xw + (size_t)win * NPOS * 96;
  for (int mt = wid; mt < 22; mt += 4) {
    int p = mt * 16 + mcol;
    int rl = (p < NPOS) ? p : (NPOS - 1);
    short8 aq[3];
#pragma unroll
    for (int kc = 0; kc < 3; ++kc)
      aq[kc] = *(const short8*)(xp + (size_t)rl * 96 + kc * 32 + grp * 8);
#pragma unroll
    for (int n = 0; n < 3; ++n) {
      f32x4 acc = {0.f, 0.f, 0.f, 0.f};
#pragma unroll
      for (int kc = 0; kc < 3; ++kc)
        acc = __builtin_amdgcn_mfma_f32_16x16x32_bf16(aq[kc], bfr[n][kc], acc, 0, 0, 0);
#pragma unroll
      for (int j = 0; j < 4; ++j)
        tl[(n * 16 + mcol) * 353 + mt * 16 + grp * 4 + j] = acc[j] + bias_n[n];
    }
  }
  __syncthreads();
  // ---- depthwise 3x3x3: one x-row (7 outputs) per thread
  for (int idx = tid; idx < 48 * 49; idx += 256) {
    int o = idx % 48, zy = idx / 48;
    int z = zy / 7, y = zy % 7;
    float wloc[27];
#pragma unroll
    for (int u = 0; u < 27; ++u) wloc[u] = dwl[o][u];
    float outr[7];
    float db = DB[ob + o];
#pragma unroll
    for (int xx = 0; xx < 7; ++xx) outr[xx] = db;
    for (int dz = -1; dz <= 1; ++dz) {
      int zz = z + dz; if ((unsigned)zz >= 7u) continue;
      for (int dy = -1; dy <= 1; ++dy) {
        int yy = y + dy; if ((unsigned)yy >= 7u) continue;
        const float* rowp = &tl[o * 353 + zz * 49 + yy * 7];
        float r[7];
#pragma unroll
        for (int u = 0; u < 7; ++u) r[u] = rowp[u];
#pragma unroll
        for (int dx = -1; dx <= 1; ++dx) {
          float w = wloc[(dz + 1) * 9 + (dy + 1) * 3 + (dx + 1)];
#pragma unroll
          for (int xx = 0; xx < 7; ++xx) {
            int sx = xx + dx;
            if (sx >= 0 && sx < 7) outr[xx] += w * r[sx];
          }
        }
      }
    }
#pragma unroll
    for (int xx = 0; xx < 7; ++xx) {
      int p = z * 49 + y * 7 + xx;
      O[((size_t)win * NPOS + p) * 96 + ob + o] = f2bf(outr[xx]);
    }
  }
}

// ---------------------------------------------------------------- K3: windowed attention via MFMA bf16 (fp32 softmax/accum)
// writes attoutT[win][c][r]  (equals the torch axis-mixing trick when read flat)
#define KSTR 104   // kb row stride (shorts)
#define VSTR 200   // vb row stride (shorts)
#define PSTR 360   // pb row stride (shorts)
__global__ __launch_bounds__(256) void k_attn(const ushort* __restrict__ q,
                                              const ushort* __restrict__ k,
                                              const ushort* __restrict__ v,
                                              float* __restrict__ attoutT) {
  int win = blockIdx.x;
  int wz = win >> 6, wy = (win >> 3) & 7, wx = win & 7;
  __shared__ __attribute__((aligned(16))) ushort kb[352 * KSTR];      // K[m][c] bf16, full
  __shared__ __attribute__((aligned(16))) ushort vb[96 * VSTR];       // V^T[c][mloc] bf16, half-streamed
  __shared__ __attribute__((aligned(16))) ushort pb[4][16 * PSTR];    // per-wave P[r][m] bf16
  __shared__ int rid[344];
  int tid = threadIdx.x, lane = tid & 63, wid = tid >> 6;

  for (int p = tid; p < NPOS; p += 256) {
    int lz = p / 49, r1 = p - lz * 49, ly = r1 / 7, lx = r1 - ly * 7;
    int az = wz * 7 + lz, ay = wy * 7 + ly, ax = wx * 7 + lx;
    int rz = (az < 49) ? 0 : ((az < 53) ? 1 : 2);
    int ry = (ay < 49) ? 0 : ((ay < 53) ? 1 : 2);
    int rx = (ax < 49) ? 0 : ((ax < 53) ? 1 : 2);
    rid[p] = rz * 9 + ry * 3 + rx;
  }
  // stage K: k[m][c] bf16 -> kb[m][c] (pad m>=343 with 0), straight vector copy
  {
    const ushort* kp = k + (size_t)win * NPOS * 96;
    for (int idx = tid; idx < 352 * 12; idx += 256) {
      int m = idx / 12, cq = idx - m * 12;
      short8 val = {0, 0, 0, 0, 0, 0, 0, 0};
      if (m < NPOS) val = *(const short8*)(kp + (size_t)m * 96 + cq * 8);
      *(short8*)&kb[m * KSTR + cq * 8] = val;
    }
  }
  __syncthreads();

  const ushort* qp = q + (size_t)win * NPOS * 96;
  const ushort* vp = v + (size_t)win * NPOS * 96;
  int mcol = lane & 15;
  int grp  = lane >> 4;
  int cb   = grp * 8;

  for (int iter = 0; iter < 6; ++iter) {
    int t = iter * 4 + wid;
    bool valid = t < 22;
    int r0 = t * 16;
    f32x4 oacc[6];
    if (valid) {
      // ---- Q fragments
      short8 aq[3];
      int r = r0 + mcol;
      int rl = (r < NPOS) ? r : (NPOS - 1);
#pragma unroll
      for (int kc = 0; kc < 3; ++kc)
        aq[kc] = *(const short8*)(qp + (size_t)rl * 96 + kc * 32 + cb);
      // ---- S = Q K^T in registers
      f32x4 sacc[22];
#pragma unroll
      for (int mf = 0; mf < 22; ++mf) {
        f32x4 acc = {0.f, 0.f, 0.f, 0.f};
#pragma unroll
        for (int kc = 0; kc < 3; ++kc) {
          short8 bfr = *(const short8*)&kb[(mf * 16 + mcol) * KSTR + kc * 32 + cb];
          acc = __builtin_amdgcn_mfma_f32_16x16x32_bf16(aq[kc], bfr, acc, 0, 0, 0);
        }
        sacc[mf] = acc;
      }
      // ---- mask + wave-local softmax
      int ridr[4];
#pragma unroll
      for (int j = 0; j < 4; ++j) {
        int rr = r0 + grp * 4 + j;
        ridr[j] = (rr < NPOS) ? rid[rr] : -2;
      }
#pragma unroll
      for (int mf = 0; mf < 22; ++mf) {
        int m = mf * 16 + mcol;
        int ridm = (m < NPOS) ? rid[m] : -1;
#pragma unroll
        for (int j = 0; j < 4; ++j)
          sacc[mf][j] = sacc[mf][j] * SCALE + ((ridm == ridr[j]) ? 0.f : -100.f);
      }
      float mx[4] = {-1e30f, -1e30f, -1e30f, -1e30f};
#pragma unroll
      for (int mf = 0; mf < 22; ++mf)
#pragma unroll
        for (int j = 0; j < 4; ++j) mx[j] = fmaxf(mx[j], sacc[mf][j]);
#pragma unroll
      for (int d = 1; d < 16; d <<= 1)
#pragma unroll
        for (int j = 0; j < 4; ++j) mx[j] = fmaxf(mx[j], __shfl_xor(mx[j], d));
      float sum[4] = {0.f, 0.f, 0.f, 0.f};
#pragma unroll
      for (int mf = 0; mf < 22; ++mf)
#pragma unroll
        for (int j = 0; j < 4; ++j) { float e = __expf(sacc[mf][j] - mx[j]); sacc[mf][j] = e; sum[j] += e; }
#pragma unroll
      for (int d = 1; d < 16; d <<= 1)
#pragma unroll
        for (int j = 0; j < 4; ++j) sum[j] += __shfl_xor(sum[j], d);
      float inv[4];
#pragma unroll
      for (int j = 0; j < 4; ++j) inv[j] = 1.f / sum[j];
      // ---- P -> own LDS slice, bf16, [r][m]
      ushort* pp = pb[wid];
#pragma unroll
      for (int mf = 0; mf < 22; ++mf) {
        int m = mf * 16 + mcol;
#pragma unroll
        for (int j = 0; j < 4; ++j)
          pp[(grp * 4 + j) * PSTR + m] = f2bf(sacc[mf][j] * inv[j]);
      }
      asm volatile("s_waitcnt lgkmcnt(0)" ::: "memory");
    }
    __syncthreads();
    // ---- V half 1 (m 0..191): v[m][c] bf16 -> vb[c][mloc]
    for (int idx = tid; idx < 12 * 192; idx += 256) {
      int cq = idx / 192, mloc = idx - cq * 192;
      short8 vv = {0, 0, 0, 0, 0, 0, 0, 0};
      if (mloc < NPOS) vv = *(const short8*)(vp + (size_t)mloc * 96 + cq * 8);
#pragma unroll
      for (int u = 0; u < 8; ++u) vb[(cq * 8 + u) * VSTR + mloc] = (ushort)vv[u];
    }
    __syncthreads();
    if (valid) {
#pragma unroll
      for (int cf = 0; cf < 6; ++cf) oacc[cf] = f32x4{0.f, 0.f, 0.f, 0.f};
      const ushort* pp = pb[wid];
#pragma unroll
      for (int kc = 0; kc < 6; ++kc) {
        short8 a = *(const short8*)&pp[mcol * PSTR + kc * 32 + cb];
#pragma unroll
        for (int cf = 0; cf < 6; ++cf) {
          short8 bfr = *(const short8*)&vb[(cf * 16 + mcol) * VSTR + kc * 32 + cb];
          oacc[cf] = __builtin_amdgcn_mfma_f32_16x16x32_bf16(a, bfr, oacc[cf], 0, 0, 0);
        }
      }
    }
    __syncthreads();
    // ---- V half 2 (m 192..351)
    for (int idx = tid; idx < 12 * 160; idx += 256) {
      int cq = idx / 160, mloc = idx - cq * 160;
      int m = 192 + mloc;
      short8 vv = {0, 0, 0, 0, 0, 0, 0, 0};
      if (m < NPOS) vv = *(const short8*)(vp + (size_t)m * 96 + cq * 8);
#pragma unroll
      for (int u = 0; u < 8; ++u) vb[(cq * 8 + u) * VSTR + mloc] = (ushort)vv[u];
    }
    __syncthreads();
    if (valid) {
      const ushort* pp = pb[wid];
#pragma unroll
      for (int kc = 0; kc < 5; ++kc) {
        short8 a = *(const short8*)&pp[mcol * PSTR + 192 + kc * 32 + cb];
#pragma unroll
        for (int cf = 0; cf < 6; ++cf) {
          short8 bfr = *(const short8*)&vb[(cf * 16 + mcol) * VSTR + kc * 32 + cb];
          oacc[cf] = __builtin_amdgcn_mfma_f32_16x16x32_bf16(a, bfr, oacc[cf], 0, 0, 0);
        }
      }
#pragma unroll
      for (int cf = 0; cf < 6; ++cf) {
        int c = cf * 16 + mcol;
#pragma unroll
        for (int j = 0; j < 4; ++j) {
          int r = r0 + grp * 4 + j;
          if (r < NPOS) attoutT[((size_t)win * CDIM + c) * NPOS + r] = oacc[cf][j];
        }
      }
    }
  }
}

// ---------------------------------------------------------------- K4: window-reverse + roll(+3) + residual -> xres[n][c]
__global__ __launch_bounds__(256) void k_merge(const float* __restrict__ x,
                                               const float* __restrict__ attoutT,
                                               float* __restrict__ xres) {
  int n0 = blockIdx.x * 64;
  __shared__ float xt[CDIM * 65];
  __shared__ int woff[64];
  int tid = threadIdx.x;
  for (int idx = tid; idx < CDIM * 64; idx += 256) {
    int c = idx >> 6, nn = idx & 63;
    xt[c * 65 + nn] = x[c * NTOT + n0 + nn];
  }
  if (tid < 64) {
    int n = n0 + tid;
    int s = n / 3136, rem = n - s * 3136, h = rem / 56, w = rem - h * 56;
    int a = (s + 53) % 56, b2 = (h + 53) % 56, d2 = (w + 53) % 56;
    int wi = (a / 7) * 64 + (b2 / 7) * 8 + (d2 / 7);
    int nnw = (a % 7) * 49 + (b2 % 7) * 7 + (d2 % 7);
    woff[tid] = wi * NPOS + nnw;  // window-local position index
  }
  __syncthreads();
  for (int idx = tid; idx < 64 * 96; idx += 256) {
    int nn = idx / 96, c = idx - nn * 96;
    // attoutT flat-read as [win][nnw][c] of the C-major array:
    int base = woff[nn];
    int wi = base / NPOS, nnw = base - wi * NPOS;
    xres[(size_t)(n0 + nn) * 96 + c] = attoutT[((size_t)wi * NPOS + nnw) * 96 + c] + xt[c * 65 + nn];
  }
}

// ---------------------------------------------------------------- K5: H = gelu(LN2(xres) @ f1w^T + f1b)
__global__ __launch_bounds__(256) void k_mlp1(const float* __restrict__ xres,
                                              const float* __restrict__ n2g, const float* __restrict__ n2b,
                                              const float* __restrict__ f1w, const float* __restrict__ f1b,
                                              float* __restrict__ H, int m_base) {
  __shared__ __attribute__((aligned(16))) float At[96 * 132];
  __shared__ __attribute__((aligned(16))) float Bt[96 * 132];
  __shared__ float mu[128], rs[128];
  int tid = threadIdx.x, ty = tid >> 4, tx = tid & 15;
  int mloc = blockIdx.x * 128, m0g = m_base + mloc, j0 = blockIdx.y * 128;
  for (int idx = tid; idx < 128 * 96; idx += 256) {
    int m = idx / 96, k = idx - m * 96;
    At[k * 132 + m] = xres[(size_t)(m0g + m) * 96 + k];
  }
  for (int idx = tid; idx < 128 * 96; idx += 256) {
    int jj = idx / 96, k = idx - jj * 96;
    Bt[k * 132 + jj] = f1w[(j0 + jj) * 96 + k];
  }
  __syncthreads();
  if (tid < 128) {
    float s = 0.f, s2 = 0.f;
    for (int k = 0; k < 96; k++) { float v = At[k * 132 + tid]; s += v; s2 += v * v; }
    float m = s * (1.f / 96.f);
    float var = s2 * (1.f / 96.f) - m * m;
    mu[tid] = m;
    rs[tid] = 1.f / sqrtf(var + 1e-5f);
  }
  __syncthreads();
  for (int idx = tid; idx < 128 * 96; idx += 256) {
    int m = idx & 127, k = idx >> 7;
    At[k * 132 + m] = (At[k * 132 + m] - mu[m]) * rs[m] * n2g[k] + n2b[k];
  }
  __syncthreads();
  float acc[8][8];
#pragma unroll
  for (int i = 0; i < 8; i++)
#pragma unroll
    for (int j = 0; j < 8; j++) acc[i][j] = 0.f;
  for (int k = 0; k < 96; k++) {
    float4 a0 = *(const float4*)&At[k * 132 + 8 * ty];
    float4 a1 = *(const float4*)&At[k * 132 + 8 * ty + 4];
    float4 b0 = *(const float4*)&Bt[k * 132 + 8 * tx];
    float4 b1 = *(const float4*)&Bt[k * 132 + 8 * tx + 4];
    float av[8] = {a0.x, a0.y, a0.z, a0.w, a1.x, a1.y, a1.z, a1.w};
    float bv2[8] = {b0.x, b0.y, b0.z, b0.w, b1.x, b1.y, b1.z, b1.w};
#pragma unroll
    for (int i = 0; i < 8; i++)
#pragma unroll
      for (int j = 0; j < 8; j++) acc[i][j] += av[i] * bv2[j];
  }
#pragma unroll
  for (int i = 0; i < 8; i++) {
#pragma unroll
    for (int j = 0; j < 8; j++) {
      float hh = acc[i][j] + f1b[j0 + 8 * tx + j];
      acc[i][j] = 0.5f * hh * (1.f + erff(hh * 0.7071067811865476f));
    }
    *(float4*)&H[(size_t)(mloc + 8 * ty + i) * HIDD + j0 + 8 * tx]     = *(float4*)&acc[i][0];
    *(float4*)&H[(size_t)(mloc + 8 * ty + i) * HIDD + j0 + 8 * tx + 4] = *(float4*)&acc[i][4];
  }
}

// ---------------------------------------------------------------- K6: out[c][n] = xres + H @ f2w^T + f2b
__global__ __launch_bounds__(256) void k_mlp2(const float* __restrict__ H,
                                              const float* __restrict__ xres,
                                              const float* __restrict__ f2w, const float* __restrict__ f2b,
                                              float* __restrict__ out, int m_base) {
  __shared__ __attribute__((aligned(16))) float At2[96 * 132];
  __shared__ float Bt2[96 * 100];
  int tid = threadIdx.x, ty = tid >> 4, tx = tid & 15;
  int mloc = blockIdx.x * 128, m0g = m_base + mloc;
  float acc[8][6];
#pragma unroll
  for (int i = 0; i < 8; i++)
#pragma unroll
    for (int j = 0; j < 6; j++) acc[i][j] = 0.f;
  for (int kb2 = 0; kb2 < HIDD; kb2 += 96) {
    __syncthreads();
    for (int idx = tid; idx < 128 * 96; idx += 256) {
      int m = idx / 96, k = idx - m * 96;
      At2[k * 132 + m] = H[(size_t)(mloc + m) * HIDD + kb2 + k];
    }
    for (int idx = tid; idx < 96 * 96; idx += 256) {
      int c = idx / 96, k = idx - c * 96;
      Bt2[k * 100 + c] = f2w[c * HIDD + kb2 + k];
    }
    __syncthreads();
    for (int k = 0; k < 96; k++) {
      float4 a0 = *(const float4*)&At2[k * 132 + 8 * ty];
      float4 a1 = *(const float4*)&At2[k * 132 + 8 * ty + 4];
      float av[8] = {a0.x, a0.y, a0.z, a0.w, a1.x, a1.y, a1.z, a1.w};
      float bv2[6];
#pragma unroll
      for (int j = 0; j < 6; j++) bv2[j] = Bt2[k * 100 + 6 * tx + j];
#pragma unroll
      for (int i = 0; i < 8; i++)
#pragma unroll
        for (int j = 0; j < 6; j++) acc[i][j] += av[i] * bv2[j];
    }
  }
#pragma unroll
  for (int i = 0; i < 8; i++)
#pragma unroll
    for (int j = 0; j < 6; j++) {
      int n = m0g + 8 * ty + i, c = 6 * tx + j;
      out[(size_t)c * NTOT + n] = acc[i][j] + f2b[c] + xres[(size_t)n * 96 + c];
    }
}

// ----------------------------------------------------------------
extern "C" void kernel_launch(void* const* d_in, const int* in_sizes, int n_in,
                              void* d_out, int out_size, void* d_ws, size_t ws_size,
                              hipStream_t stream) {
  const float* x   = (const float*)d_in[0];
  const float* n1g = (const float*)d_in[1];
  const float* n1b = (const float*)d_in[2];
  const float* wq  = (const float*)d_in[3];
  const float* bq  = (const float*)d_in[4];
  const float* wk  = (const float*)d_in[5];
  const float* bk  = (const float*)d_in[6];
  const float* wv  = (const float*)d_in[7];
  const float* bv  = (const float*)d_in[8];
  const float* dqw = (const float*)d_in[9];
  const float* dqb = (const float*)d_in[10];
  const float* dkw = (const float*)d_in[11];
  const float* dkb = (const float*)d_in[12];
  const float* dvw = (const float*)d_in[13];
  const float* dvb = (const float*)d_in[14];
  const float* n2g = (const float*)d_in[15];
  const float* n2b = (const float*)d_in[16];
  const float* f1w = (const float*)d_in[17];
  const float* f1b = (const float*)d_in[18];
  const float* f2w = (const float*)d_in[19];
  const float* f2b = (const float*)d_in[20];
  float* out = (float*)d_out;
  float* ws = (float*)d_ws;

  const size_t need = (size_t)3 * SLOT * 4;
  if (ws_size < need) {
    fprintf(stderr, "kernel_launch: ws_size %zu < needed %zu -- aborting launch\n", ws_size, need);
    return;
  }

  // slot A: Xw bf16 (K1->K2, first half), then attoutT fp32 (K3->K4, full)
  // slot B: q bf16 (first half) + k bf16 (second half) (K2->K3), then xres fp32 (K4->K6)
  // slot C: v bf16 (first half) (K2->K3), then H fp32 chunk (K5->K6)
  ushort* Xw_bf  = (ushort*)ws;
  float*  attoutT = ws;
  ushort* q_bf   = (ushort*)(ws + (size_t)SLOT);
  ushort* k_bf   = q_bf + (size_t)SLOT;
  float*  xres   = ws + (size_t)SLOT;
  ushort* v_bf   = (ushort*)(ws + (size_t)2 * SLOT);
  float*  Hbuf   = ws + (size_t)2 * SLOT;

  k_ln1<<<dim3(NWIN, 6), 256, 0, stream>>>(x, n1g, n1b, Xw_bf);
  k_qkv<<<dim3(NWIN, 3, 2), 256, 0, stream>>>(Xw_bf, wq, bq, dqw, dqb, wk, bk, dkw, dkb,
                                              wv, bv, dvw, dvb, q_bf, k_bf, v_bf);
  k_attn<<<NWIN, 256, 0, stream>>>(q_bf, k_bf, v_bf, attoutT);
  k_merge<<<NTOT / 64, 256, 0, stream>>>(x, attoutT, xres);
  for (int ch = 0; ch < 4; ch++) {
    int m_base = ch * (NTOT / 4);
    k_mlp1<<<dim3(NTOT / 4 / 128, 3), 256, 0, stream>>>(xres, n2g, n2b, f1w, f1b, Hbuf, m_base);
    k_mlp2<<<NTOT / 4 / 128, 256, 0, stream>>>(Hbuf, xres, f2w, f2b, out, m_base);
  }
}

// Round 10
// 838.561 us; speedup vs baseline: 6.1101x; 1.8843x over previous
//
#include <hip/hip_runtime.h>
#include <cstdio>

#define NTOT 175616   // 56^3
#define CDIM 96
#define NPOS 343      // 7^3
#define NWIN 512      // 8^3
#define HIDD 384
#define SLOT 16859136 // NWIN*CDIM*NPOS = NTOT*CDIM
#define SCALE 0.10206207261596577f  // 1/sqrt(96)

typedef __attribute__((ext_vector_type(8))) short short8;
typedef __attribute__((ext_vector_type(4))) float f32x4;

__device__ inline ushort f2bf(float f) {
  union { float f; unsigned u; } v; v.f = f;
  unsigned r = v.u + 0x7FFFu + ((v.u >> 16) & 1u);
  return (ushort)(r >> 16);
}

// ---------------------------------------------------------------- K1: LN1 + roll(-3) + window partition -> Xw[win][p][c] bf16
__global__ __launch_bounds__(256) void k_ln1(const float* __restrict__ x,
                                             const float* __restrict__ g,
                                             const float* __restrict__ b,
                                             ushort* __restrict__ Xw) {
  int win = blockIdx.x;
  int p0 = blockIdx.y * 64;
  int cnt = min(64, NPOS - p0);
  int wz = win >> 6, wy = (win >> 3) & 7, wx = win & 7;
  __shared__ float raw[CDIM][65];
  __shared__ float psum[4][64], psq[4][64];
  __shared__ float mean[64], rstd[64];
  int tid = threadIdx.x;
  for (int idx = tid; idx < CDIM * 64; idx += 256) {
    int c = idx >> 6, pp = idx & 63;
    float v = 0.f;
    if (pp < cnt) {
      int p = p0 + pp;
      int lz = p / 49, ly = (p / 7) % 7, lx = p % 7;
      int s = (wz * 7 + lz + 3) % 56;
      int h = (wy * 7 + ly + 3) % 56;
      int w = (wx * 7 + lx + 3) % 56;
      v = x[c * NTOT + (s * 3136 + h * 56 + w)];
    }
    raw[c][pp] = v;
  }
  __syncthreads();
  {
    int pp = tid & 63, grp = tid >> 6;
    float s = 0.f, s2 = 0.f;
    for (int i = 0; i < 24; i++) { float v = raw[grp * 24 + i][pp]; s += v; s2 += v * v; }
    psum[grp][pp] = s; psq[grp][pp] = s2;
  }
  __syncthreads();
  if (tid < 64) {
    float s = psum[0][tid] + psum[1][tid] + psum[2][tid] + psum[3][tid];
    float s2 = psq[0][tid] + psq[1][tid] + psq[2][tid] + psq[3][tid];
    float m = s * (1.f / 96.f);
    float var = s2 * (1.f / 96.f) - m * m;
    mean[tid] = m;
    rstd[tid] = 1.f / sqrtf(var + 1e-5f);
  }
  __syncthreads();
  for (int idx = tid; idx < cnt * 96; idx += 256) {
    int pp = idx / 96, c = idx - pp * 96;
    float v = (raw[c][pp] - mean[pp]) * rstd[pp] * g[c] + b[c];
    Xw[((size_t)win * NPOS + p0 + pp) * 96 + c] = f2bf(v);
  }
}

// ---------------------------------------------------------------- K2: MFMA conv1x1 + depthwise 3x3x3 per window
__global__ __launch_bounds__(256) void k_qkv(
    const ushort* __restrict__ Xw,
    const float* __restrict__ wq, const float* __restrict__ bq, const float* __restrict__ dqw, const float* __restrict__ dqb,
    const float* __restrict__ wk, const float* __restrict__ bk, const float* __restrict__ dkw, const float* __restrict__ dkb,
    const float* __restrict__ wv, const float* __restrict__ bv, const float* __restrict__ dvw, const float* __restrict__ dvb,
    ushort* __restrict__ qo, ushort* __restrict__ ko, ushort* __restrict__ vo) {
  int win = blockIdx.x, t = blockIdx.y, ob = blockIdx.z * 48;
  const float *W, *B, *DW, *DB; ushort* O;
  if (t == 0)      { W = wq; B = bq; DW = dqw; DB = dqb; O = qo; }
  else if (t == 1) { W = wk; B = bk; DW = dkw; DB = dkb; O = ko; }
  else             { W = wv; B = bv; DW = dvw; DB = dvb; O = vo; }
  __shared__ __attribute__((aligned(16))) float tl[48 * 353];   // conv1x1 out [olocal][p]
  __shared__ float dwl[48][27];
  int tid = threadIdx.x, lane = tid & 63, wid = tid >> 6;
  int mcol = lane & 15, grp = lane >> 4;

  for (int idx = tid; idx < 48 * 27; idx += 256)
    dwl[idx / 27][idx % 27] = DW[(ob + idx / 27) * 27 + idx % 27];

  short8 bfr[3][3];
  float bias_n[3];
#pragma unroll
  for (int n = 0; n < 3; ++n) {
    int o = ob + n * 16 + mcol;
    bias_n[n] = B[o];
#pragma unroll
    for (int kc = 0; kc < 3; ++kc) {
      const float* src = W + (size_t)o * 96 + kc * 32 + grp * 8;
      float4 f0 = *(const float4*)(src);
      float4 f1 = *(const float4*)(src + 4);
      short8 a;
      a[0] = (short)f2bf(f0.x); a[1] = (short)f2bf(f0.y); a[2] = (short)f2bf(f0.z); a[3] = (short)f2bf(f0.w);
      a[4] = (short)f2bf(f1.x); a[5] = (short)f2bf(f1.y); a[6] = (short)f2bf(f1.z); a[7] = (short)f2bf(f1.w);
      bfr[n][kc] = a;
    }
  }
  const ushort* xp = Xw + (size_t)win * NPOS * 96;
  for (int mt = wid; mt < 22; mt += 4) {
    int p = mt * 16 + mcol;
    int rl = (p < NPOS) ? p : (NPOS - 1);
    short8 aq[3];
#pragma unroll
    for (int kc = 0; kc < 3; ++kc)
      aq[kc] = *(const short8*)(xp + (size_t)rl * 96 + kc * 32 + grp * 8);
#pragma unroll
    for (int n = 0; n < 3; ++n) {
      f32x4 acc = {0.f, 0.f, 0.f, 0.f};
#pragma unroll
      for (int kc = 0; kc < 3; ++kc)
        acc = __builtin_amdgcn_mfma_f32_16x16x32_bf16(aq[kc], bfr[n][kc], acc, 0, 0, 0);
#pragma unroll
      for (int j = 0; j < 4; ++j)
        tl[(n * 16 + mcol) * 353 + mt * 16 + grp * 4 + j] = acc[j] + bias_n[n];
    }
  }
  __syncthreads();
  for (int idx = tid; idx < 48 * 49; idx += 256) {
    int o = idx % 48, zy = idx / 48;
    int z = zy / 7, y = zy % 7;
    float wloc[27];
#pragma unroll
    for (int u = 0; u < 27; ++u) wloc[u] = dwl[o][u];
    float outr[7];
    float db = DB[ob + o];
#pragma unroll
    for (int xx = 0; xx < 7; ++xx) outr[xx] = db;
    for (int dz = -1; dz <= 1; ++dz) {
      int zz = z + dz; if ((unsigned)zz >= 7u) continue;
      for (int dy = -1; dy <= 1; ++dy) {
        int yy = y + dy; if ((unsigned)yy >= 7u) continue;
        const float* rowp = &tl[o * 353 + zz * 49 + yy * 7];
        float r[7];
#pragma unroll
        for (int u = 0; u < 7; ++u) r[u] = rowp[u];
#pragma unroll
        for (int dx = -1; dx <= 1; ++dx) {
          float w = wloc[(dz + 1) * 9 + (dy + 1) * 3 + (dx + 1)];
#pragma unroll
          for (int xx = 0; xx < 7; ++xx) {
            int sx = xx + dx;
            if (sx >= 0 && sx < 7) outr[xx] += w * r[sx];
          }
        }
      }
    }
#pragma unroll
    for (int xx = 0; xx < 7; ++xx) {
      int p = z * 49 + y * 7 + xx;
      O[((size_t)win * NPOS + p) * 96 + ob + o] = f2bf(outr[xx]);
    }
  }
}

// ---------------------------------------------------------------- K3: windowed attention via MFMA bf16 (fp32 softmax/accum)
#define KSTR 104
#define VSTR 200
#define PSTR 360
__global__ __launch_bounds__(256) void k_attn(const ushort* __restrict__ q,
                                              const ushort* __restrict__ k,
                                              const ushort* __restrict__ v,
                                              float* __restrict__ attoutT) {
  int win = blockIdx.x;
  int wz = win >> 6, wy = (win >> 3) & 7, wx = win & 7;
  __shared__ __attribute__((aligned(16))) ushort kb[352 * KSTR];
  __shared__ __attribute__((aligned(16))) ushort vb[96 * VSTR];
  __shared__ __attribute__((aligned(16))) ushort pb[4][16 * PSTR];
  __shared__ int rid[344];
  int tid = threadIdx.x, lane = tid & 63, wid = tid >> 6;

  for (int p = tid; p < NPOS; p += 256) {
    int lz = p / 49, r1 = p - lz * 49, ly = r1 / 7, lx = r1 - ly * 7;
    int az = wz * 7 + lz, ay = wy * 7 + ly, ax = wx * 7 + lx;
    int rz = (az < 49) ? 0 : ((az < 53) ? 1 : 2);
    int ry = (ay < 49) ? 0 : ((ay < 53) ? 1 : 2);
    int rx = (ax < 49) ? 0 : ((ax < 53) ? 1 : 2);
    rid[p] = rz * 9 + ry * 3 + rx;
  }
  {
    const ushort* kp = k + (size_t)win * NPOS * 96;
    for (int idx = tid; idx < 352 * 12; idx += 256) {
      int m = idx / 12, cq = idx - m * 12;
      short8 val = {0, 0, 0, 0, 0, 0, 0, 0};
      if (m < NPOS) val = *(const short8*)(kp + (size_t)m * 96 + cq * 8);
      *(short8*)&kb[m * KSTR + cq * 8] = val;
    }
  }
  __syncthreads();

  const ushort* qp = q + (size_t)win * NPOS * 96;
  const ushort* vp = v + (size_t)win * NPOS * 96;
  int mcol = lane & 15;
  int grp  = lane >> 4;
  int cb   = grp * 8;

  for (int iter = 0; iter < 6; ++iter) {
    int t = iter * 4 + wid;
    bool valid = t < 22;
    int r0 = t * 16;
    f32x4 oacc[6];
    if (valid) {
      short8 aq[3];
      int r = r0 + mcol;
      int rl = (r < NPOS) ? r : (NPOS - 1);
#pragma unroll
      for (int kc = 0; kc < 3; ++kc)
        aq[kc] = *(const short8*)(qp + (size_t)rl * 96 + kc * 32 + cb);
      f32x4 sacc[22];
#pragma unroll
      for (int mf = 0; mf < 22; ++mf) {
        f32x4 acc = {0.f, 0.f, 0.f, 0.f};
#pragma unroll
        for (int kc = 0; kc < 3; ++kc) {
          short8 bfr = *(const short8*)&kb[(mf * 16 + mcol) * KSTR + kc * 32 + cb];
          acc = __builtin_amdgcn_mfma_f32_16x16x32_bf16(aq[kc], bfr, acc, 0, 0, 0);
        }
        sacc[mf] = acc;
      }
      int ridr[4];
#pragma unroll
      for (int j = 0; j < 4; ++j) {
        int rr = r0 + grp * 4 + j;
        ridr[j] = (rr < NPOS) ? rid[rr] : -2;
      }
#pragma unroll
      for (int mf = 0; mf < 22; ++mf) {
        int m = mf * 16 + mcol;
        int ridm = (m < NPOS) ? rid[m] : -1;
#pragma unroll
        for (int j = 0; j < 4; ++j)
          sacc[mf][j] = sacc[mf][j] * SCALE + ((ridm == ridr[j]) ? 0.f : -100.f);
      }
      float mx[4] = {-1e30f, -1e30f, -1e30f, -1e30f};
#pragma unroll
      for (int mf = 0; mf < 22; ++mf)
#pragma unroll
        for (int j = 0; j < 4; ++j) mx[j] = fmaxf(mx[j], sacc[mf][j]);
#pragma unroll
      for (int d = 1; d < 16; d <<= 1)
#pragma unroll
        for (int j = 0; j < 4; ++j) mx[j] = fmaxf(mx[j], __shfl_xor(mx[j], d));
      float sum[4] = {0.f, 0.f, 0.f, 0.f};
#pragma unroll
      for (int mf = 0; mf < 22; ++mf)
#pragma unroll
        for (int j = 0; j < 4; ++j) { float e = __expf(sacc[mf][j] - mx[j]); sacc[mf][j] = e; sum[j] += e; }
#pragma unroll
      for (int d = 1; d < 16; d <<= 1)
#pragma unroll
        for (int j = 0; j < 4; ++j) sum[j] += __shfl_xor(sum[j], d);
      float inv[4];
#pragma unroll
      for (int j = 0; j < 4; ++j) inv[j] = 1.f / sum[j];
      ushort* pp = pb[wid];
#pragma unroll
      for (int mf = 0; mf < 22; ++mf) {
        int m = mf * 16 + mcol;
#pragma unroll
        for (int j = 0; j < 4; ++j)
          pp[(grp * 4 + j) * PSTR + m] = f2bf(sacc[mf][j] * inv[j]);
      }
      asm volatile("s_waitcnt lgkmcnt(0)" ::: "memory");
    }
    __syncthreads();
    for (int idx = tid; idx < 12 * 192; idx += 256) {
      int cq = idx / 192, mloc = idx - cq * 192;
      short8 vv = {0, 0, 0, 0, 0, 0, 0, 0};
      if (mloc < NPOS) vv = *(const short8*)(vp + (size_t)mloc * 96 + cq * 8);
#pragma unroll
      for (int u = 0; u < 8; ++u) vb[(cq * 8 + u) * VSTR + mloc] = (ushort)vv[u];
    }
    __syncthreads();
    if (valid) {
#pragma unroll
      for (int cf = 0; cf < 6; ++cf) oacc[cf] = f32x4{0.f, 0.f, 0.f, 0.f};
      const ushort* pp = pb[wid];
#pragma unroll
      for (int kc = 0; kc < 6; ++kc) {
        short8 a = *(const short8*)&pp[mcol * PSTR + kc * 32 + cb];
#pragma unroll
        for (int cf = 0; cf < 6; ++cf) {
          short8 bfr = *(const short8*)&vb[(cf * 16 + mcol) * VSTR + kc * 32 + cb];
          oacc[cf] = __builtin_amdgcn_mfma_f32_16x16x32_bf16(a, bfr, oacc[cf], 0, 0, 0);
        }
      }
    }
    __syncthreads();
    for (int idx = tid; idx < 12 * 160; idx += 256) {
      int cq = idx / 160, mloc = idx - cq * 160;
      int m = 192 + mloc;
      short8 vv = {0, 0, 0, 0, 0, 0, 0, 0};
      if (m < NPOS) vv = *(const short8*)(vp + (size_t)m * 96 + cq * 8);
#pragma unroll
      for (int u = 0; u < 8; ++u) vb[(cq * 8 + u) * VSTR + mloc] = (ushort)vv[u];
    }
    __syncthreads();
    if (valid) {
      const ushort* pp = pb[wid];
#pragma unroll
      for (int kc = 0; kc < 5; ++kc) {
        short8 a = *(const short8*)&pp[mcol * PSTR + 192 + kc * 32 + cb];
#pragma unroll
        for (int cf = 0; cf < 6; ++cf) {
          short8 bfr = *(const short8*)&vb[(cf * 16 + mcol) * VSTR + kc * 32 + cb];
          oacc[cf] = __builtin_amdgcn_mfma_f32_16x16x32_bf16(a, bfr, oacc[cf], 0, 0, 0);
        }
      }
#pragma unroll
      for (int cf = 0; cf < 6; ++cf) {
        int c = cf * 16 + mcol;
#pragma unroll
        for (int j = 0; j < 4; ++j) {
          int r = r0 + grp * 4 + j;
          if (r < NPOS) attoutT[((size_t)win * CDIM + c) * NPOS + r] = oacc[cf][j];
        }
      }
    }
  }
}

// ---------------------------------------------------------------- K4: window-reverse + roll(+3) + residual -> xres[n][c]; fused LN2 stats
__global__ __launch_bounds__(256) void k_merge(const float* __restrict__ x,
                                               const float* __restrict__ attoutT,
                                               float* __restrict__ xres,
                                               float* __restrict__ meang,
                                               float* __restrict__ rstdg) {
  int n0 = blockIdx.x * 64;
  __shared__ float xt[CDIM * 65];
  __shared__ float res[64 * 97];
  __shared__ int woff[64];
  __shared__ float psum[4][64], psq[4][64];
  int tid = threadIdx.x;
  for (int idx = tid; idx < CDIM * 64; idx += 256) {
    int c = idx >> 6, nn = idx & 63;
    xt[c * 65 + nn] = x[c * NTOT + n0 + nn];
  }
  if (tid < 64) {
    int n = n0 + tid;
    int s = n / 3136, rem = n - s * 3136, h = rem / 56, w = rem - h * 56;
    int a = (s + 53) % 56, b2 = (h + 53) % 56, d2 = (w + 53) % 56;
    int wi = (a / 7) * 64 + (b2 / 7) * 8 + (d2 / 7);
    int nnw = (a % 7) * 49 + (b2 % 7) * 7 + (d2 % 7);
    woff[tid] = wi * NPOS + nnw;
  }
  __syncthreads();
  for (int idx = tid; idx < 64 * 96; idx += 256) {
    int nn = idx / 96, c = idx - nn * 96;
    float vv = attoutT[(size_t)woff[nn] * 96 + c] + xt[c * 65 + nn];
    res[nn * 97 + c] = vv;
    xres[(size_t)(n0 + nn) * 96 + c] = vv;
  }
  __syncthreads();
  {
    int pp = tid & 63, grp = tid >> 6;
    float s = 0.f, s2 = 0.f;
    for (int i = 0; i < 24; i++) { float vv = res[pp * 97 + grp * 24 + i]; s += vv; s2 += vv * vv; }
    psum[grp][pp] = s; psq[grp][pp] = s2;
  }
  __syncthreads();
  if (tid < 64) {
    float s = psum[0][tid] + psum[1][tid] + psum[2][tid] + psum[3][tid];
    float s2 = psq[0][tid] + psq[1][tid] + psq[2][tid] + psq[3][tid];
    float m = s * (1.f / 96.f);
    float var = s2 * (1.f / 96.f) - m * m;
    meang[n0 + tid] = m;
    rstdg[n0 + tid] = 1.f / sqrtf(var + 1e-5f);
  }
}

// ---------------------------------------------------------------- K5: H = gelu(LN2(xres) @ f1w^T + f1b), MFMA, H bf16
__global__ __launch_bounds__(256) void k_mlp1(const float* __restrict__ xres,
                                              const float* __restrict__ meang, const float* __restrict__ rstdg,
                                              const float* __restrict__ n2g, const float* __restrict__ n2b,
                                              const float* __restrict__ f1w, const float* __restrict__ f1b,
                                              ushort* __restrict__ H) {
  __shared__ __attribute__((aligned(16))) ushort f1s[384 * 104];
  __shared__ float f1bs[384];
  int tid = threadIdx.x, lane = tid & 63, wid = tid >> 6;
  int mcol = lane & 15, grp = lane >> 4;
  for (int idx = tid; idx < 384 * 96; idx += 256) {
    int j = idx / 96, k = idx - j * 96;
    f1s[j * 104 + k] = f2bf(f1w[(size_t)j * 96 + k]);
  }
  for (int idx = tid; idx < 384; idx += 256) f1bs[idx] = f1b[idx];
  int r0 = blockIdx.x * 64 + wid * 16;
  int r = r0 + mcol;
  float mu = meang[r], rs = rstdg[r];
  short8 aq[3];
#pragma unroll
  for (int kc = 0; kc < 3; ++kc) {
    const float* src = xres + (size_t)r * 96 + kc * 32 + grp * 8;
    float4 f0 = *(const float4*)src;
    float4 f1 = *(const float4*)(src + 4);
    const float* gg = n2g + kc * 32 + grp * 8;
    const float* bb = n2b + kc * 32 + grp * 8;
    float4 g0 = *(const float4*)gg, g1 = *(const float4*)(gg + 4);
    float4 b0 = *(const float4*)bb, b1 = *(const float4*)(bb + 4);
    short8 a;
    a[0] = (short)f2bf((f0.x - mu) * rs * g0.x + b0.x);
    a[1] = (short)f2bf((f0.y - mu) * rs * g0.y + b0.y);
    a[2] = (short)f2bf((f0.z - mu) * rs * g0.z + b0.z);
    a[3] = (short)f2bf((f0.w - mu) * rs * g0.w + b0.w);
    a[4] = (short)f2bf((f1.x - mu) * rs * g1.x + b1.x);
    a[5] = (short)f2bf((f1.y - mu) * rs * g1.y + b1.y);
    a[6] = (short)f2bf((f1.z - mu) * rs * g1.z + b1.z);
    a[7] = (short)f2bf((f1.w - mu) * rs * g1.w + b1.w);
    aq[kc] = a;
  }
  __syncthreads();
#pragma unroll
  for (int jt = 0; jt < 24; ++jt) {
    f32x4 acc = {0.f, 0.f, 0.f, 0.f};
#pragma unroll
    for (int kc = 0; kc < 3; ++kc)
      acc = __builtin_amdgcn_mfma_f32_16x16x32_bf16(aq[kc], *(const short8*)&f1s[(jt * 16 + mcol) * 104 + kc * 32 + grp * 8], acc, 0, 0, 0);
    float bias = f1bs[jt * 16 + mcol];
#pragma unroll
    for (int j = 0; j < 4; ++j) {
      float hh = acc[j] + bias;
      hh = 0.5f * hh * (1.f + erff(hh * 0.7071067811865476f));
      H[(size_t)(r0 + grp * 4 + j) * HIDD + jt * 16 + mcol] = f2bf(hh);
    }
  }
}

// ---------------------------------------------------------------- K6: out[c][n] = xres + H @ f2w^T + f2b, MFMA
__global__ __launch_bounds__(256) void k_mlp2(const ushort* __restrict__ H,
                                              const float* __restrict__ xres,
                                              const float* __restrict__ f2w, const float* __restrict__ f2b,
                                              float* __restrict__ out) {
  __shared__ __attribute__((aligned(16))) ushort f2s[96 * 392];
  int tid = threadIdx.x, lane = tid & 63, wid = tid >> 6;
  int mcol = lane & 15, grp = lane >> 4;
  for (int idx = tid; idx < 96 * 384; idx += 256) {
    int c = idx / 384, k = idx - c * 384;
    f2s[c * 392 + k] = f2bf(f2w[(size_t)c * 384 + k]);
  }
  int r0 = blockIdx.x * 64 + wid * 16;
  int r = r0 + mcol;
  short8 aq[12];
#pragma unroll
  for (int kc = 0; kc < 12; ++kc)
    aq[kc] = *(const short8*)(H + (size_t)r * HIDD + kc * 32 + grp * 8);
  __syncthreads();
  f32x4 acc[6];
#pragma unroll
  for (int cf = 0; cf < 6; ++cf) acc[cf] = f32x4{0.f, 0.f, 0.f, 0.f};
#pragma unroll
  for (int kc = 0; kc < 12; ++kc)
#pragma unroll
    for (int cf = 0; cf < 6; ++cf)
      acc[cf] = __builtin_amdgcn_mfma_f32_16x16x32_bf16(aq[kc], *(const short8*)&f2s[(cf * 16 + mcol) * 392 + kc * 32 + grp * 8], acc[cf], 0, 0, 0);
#pragma unroll
  for (int cf = 0; cf < 6; ++cf) {
    int c = cf * 16 + mcol;
    float fb = f2b[c];
#pragma unroll
    for (int j = 0; j < 4; ++j) {
      int n = r0 + grp * 4 + j;
      out[(size_t)c * NTOT + n] = acc[cf][j] + fb + xres[(size_t)n * 96 + c];
    }
  }
}

// ----------------------------------------------------------------
extern "C" void kernel_launch(void* const* d_in, const int* in_sizes, int n_in,
                              void* d_out, int out_size, void* d_ws, size_t ws_size,
                              hipStream_t stream) {
  const float* x   = (const float*)d_in[0];
  const float* n1g = (const float*)d_in[1];
  const float* n1b = (const float*)d_in[2];
  const float* wq  = (const float*)d_in[3];
  const float* bq  = (const float*)d_in[4];
  const float* wk  = (const float*)d_in[5];
  const float* bk  = (const float*)d_in[6];
  const float* wv  = (const float*)d_in[7];
  const float* bv  = (const float*)d_in[8];
  const float* dqw = (const float*)d_in[9];
  const float* dqb = (const float*)d_in[10];
  const float* dkw = (const float*)d_in[11];
  const float* dkb = (const float*)d_in[12];
  const float* dvw = (const float*)d_in[13];
  const float* dvb = (const float*)d_in[14];
  const float* n2g = (const float*)d_in[15];
  const float* n2b = (const float*)d_in[16];
  const float* f1w = (const float*)d_in[17];
  const float* f1b = (const float*)d_in[18];
  const float* f2w = (const float*)d_in[19];
  const float* f2b = (const float*)d_in[20];
  float* out = (float*)d_out;
  float* ws = (float*)d_ws;

  const size_t need = ((size_t)3 * SLOT + 2 * NTOT) * 4;
  if (ws_size < need) {
    fprintf(stderr, "kernel_launch: ws_size %zu < needed %zu -- aborting launch\n", ws_size, need);
    return;
  }

  // slot A: Xw bf16 (K1->K2, first half), attoutT fp32 (K3->K4)
  // slot B: q bf16 + k bf16 (K2->K3)
  // slot C: v bf16 first half (K2->K3), then xres fp32 (K4->K6)
  // slots A+B: H bf16 full (K5->K6, contiguous 2 slots)
  // tail: meang/rstdg
  ushort* Xw_bf   = (ushort*)ws;
  float*  attoutT = ws;
  ushort* q_bf    = (ushort*)(ws + (size_t)SLOT);
  ushort* k_bf    = q_bf + (size_t)SLOT;
  ushort* v_bf    = (ushort*)(ws + (size_t)2 * SLOT);
  float*  xres    = ws + (size_t)2 * SLOT;
  ushort* Hbuf    = (ushort*)ws;
  float*  meang   = ws + (size_t)3 * SLOT;
  float*  rstdg   = meang + NTOT;

  k_ln1<<<dim3(NWIN, 6), 256, 0, stream>>>(x, n1g, n1b, Xw_bf);
  k_qkv<<<dim3(NWIN, 3, 2), 256, 0, stream>>>(Xw_bf, wq, bq, dqw, dqb, wk, bk, dkw, dkb,
                                              wv, bv, dvw, dvb, q_bf, k_bf, v_bf);
  k_attn<<<NWIN, 256, 0, stream>>>(q_bf, k_bf, v_bf, attoutT);
  k_merge<<<NTOT / 64, 256, 0, stream>>>(x, attoutT, xres, meang, rstdg);
  k_mlp1<<<NTOT / 64, 256, 0, stream>>>(xres, meang, rstdg, n2g, n2b, f1w, f1b, Hbuf);
  k_mlp2<<<NTOT / 64, 256, 0, stream>>>(Hbuf, xres, f2w, f2b, out);
}